// Round 1
// 214.301 us; speedup vs baseline: 1.0040x; 1.0040x over previous
//
#include <hip/hip_runtime.h>
#include <hip/hip_bf16.h>

#define D_MODEL 1024
#define D_STATE 16
#define L_SEQ 2048
#define B_SZ 4
#define M_ROWS (B_SZ * L_SEQ)   // 8192
#define N_CHUNK 32               // chunks per sequence
#define C_LEN 64                 // timesteps per chunk (32*64 = 2048)

typedef __attribute__((ext_vector_type(8))) short short8;
typedef __attribute__((ext_vector_type(4))) float f32x4;

// Raw barrier (no waitcnt) and the per-K-tile gate: counted vmcnt (never 0 in
// steady state) + lgkm drain (WAR protection for the slot about to be staged).
#define SBAR()  asm volatile("s_barrier" ::: "memory")
#define GATE(N) asm volatile("s_waitcnt vmcnt(" #N ") lgkmcnt(0)\n\ts_barrier" ::: "memory")

typedef const unsigned short __attribute__((address_space(1))) gas_us;
typedef unsigned short __attribute__((address_space(3))) las_us;
static __device__ __forceinline__ void gload16(const unsigned short* g, unsigned short* l) {
    // global -> LDS DMA, 16B per lane, dest = wave-uniform base + lane*16
    __builtin_amdgcn_global_load_lds((gas_us*)g, (las_us*)l, 16, 0, 0);
}

static __device__ __forceinline__ unsigned short f2bf(float f) {
    unsigned int u = __float_as_uint(f);
    unsigned int r = (u + 0x7FFFu + ((u >> 16) & 1u)) >> 16;   // RNE
    return (unsigned short)r;
}
static __device__ __forceinline__ float bf2f(unsigned short u) {
    return __uint_as_float(((unsigned int)u) << 16);
}

// ---------------- convert fp32 -> bf16 (weights) ----------------
__global__ void conv_bf16_kernel(const float* __restrict__ src,
                                 unsigned short* __restrict__ dst, int n4) {
    int i = blockIdx.x * blockDim.x + threadIdx.x;
    if (i < n4) {
        float4 v = ((const float4*)src)[i];
        ushort4 o;
        o.x = f2bf(v.x); o.y = f2bf(v.y); o.z = f2bf(v.z); o.w = f2bf(v.w);
        ((ushort4*)dst)[i] = o;
    }
}

// ---------------- LayerNorm: x (8192 x 1024) -> xn bf16 ----------------
__global__ __launch_bounds__(256) void ln_kernel(const float* __restrict__ x,
                                                 const float* __restrict__ g,
                                                 const float* __restrict__ b,
                                                 unsigned short* __restrict__ xn) {
    int row = blockIdx.x;
    int t = threadIdx.x;
    const float4* xr = (const float4*)(x + (size_t)row * D_MODEL);
    float4 v = xr[t];
    float s  = v.x + v.y + v.z + v.w;
    float ss = v.x * v.x + v.y * v.y + v.z * v.z + v.w * v.w;
    #pragma unroll
    for (int o = 32; o > 0; o >>= 1) {
        s  += __shfl_down(s,  o);
        ss += __shfl_down(ss, o);
    }
    __shared__ float sbuf[8];
    int wid = t >> 6;
    if ((t & 63) == 0) { sbuf[wid] = s; sbuf[4 + wid] = ss; }
    __syncthreads();
    float S  = sbuf[0] + sbuf[1] + sbuf[2] + sbuf[3];
    float SS = sbuf[4] + sbuf[5] + sbuf[6] + sbuf[7];
    float mu  = S * (1.0f / D_MODEL);
    float var = SS * (1.0f / D_MODEL) - mu * mu;
    float inv = rsqrtf(var + 1e-5f);
    float4 gv = ((const float4*)g)[t];
    float4 bv = ((const float4*)b)[t];
    ushort4 o;
    o.x = f2bf((v.x - mu) * inv * gv.x + bv.x);
    o.y = f2bf((v.y - mu) * inv * gv.y + bv.y);
    o.z = f2bf((v.z - mu) * inv * gv.z + bv.z);
    o.w = f2bf((v.w - mu) * inv * gv.w + bv.w);
    ((ushort4*)(xn + (size_t)row * D_MODEL))[t] = o;
}

// 16 MFMA cluster: 4 m-frags x 4 n-frags
#define MFMA16(ACC, I0, AV, BV) { \
    _Pragma("unroll") for (int i_ = 0; i_ < 4; ++i_) { \
        _Pragma("unroll") for (int jf_ = 0; jf_ < 4; ++jf_) \
            ACC[(I0) + i_][jf_] = __builtin_amdgcn_mfma_f32_16x16x32_bf16( \
                AV[i_], BV[jf_], ACC[(I0) + i_][jf_], 0, 0, 0); } }

// ============================================================================
// GEMM1: 256x256 tile, BK=32, 4 LDS slots, lead-3 counted-vmcnt pipeline.
// 8 waves (2m x 4n), wave tile 128x64, acc[8][4].
// LDS tile layout per (slot, matrix): 16 subtiles of [16 rows][32 k] bf16
// (1024B each), XOR-swizzled: byte ^= ((byte>>9)&1)<<5 (i.e. k ^= 16 when
// row&8). Staged via global_load_lds with INVERSE-swizzled global source;
// ds_read applies the same swizzle. 4-way residual conflict (acceptable).
// ============================================================================
#define STAGE1A(J) { size_t ko_ = (size_t)(J) * 32; int so_ = ((J) & 3) * 16384; \
    gload16(pA0 + ko_, dA0 + so_); gload16(pA1 + ko_, dA1 + so_); }
#define STAGE1B(J) { size_t ko_ = (size_t)(J) * 32; int so_ = ((J) & 3) * 16384; \
    gload16(pB0 + ko_, dB0 + so_); gload16(pB1 + ko_, dB1 + so_); }

#define G1_TILE(J, DOSTAGE, TRAIL) { \
    const int slot_ = (J) & 3; \
    const char* rA_ = ldsA_rd + slot_ * 32768; \
    const char* rB_ = ldsB_rd + slot_ * 32768; \
    short8 av[4], bv[4]; \
    _Pragma("unroll") for (int j_ = 0; j_ < 4; ++j_) bv[j_] = *(const short8*)(rB_ + j_ * 1024); \
    _Pragma("unroll") for (int i_ = 0; i_ < 4; ++i_) av[i_] = *(const short8*)(rA_ + i_ * 1024); \
    if (DOSTAGE) { STAGE1A((J) + 3); } \
    SBAR(); \
    __builtin_amdgcn_s_setprio(1); \
    MFMA16(acc, 0, av, bv); \
    __builtin_amdgcn_s_setprio(0); \
    SBAR(); \
    _Pragma("unroll") for (int i_ = 0; i_ < 4; ++i_) av[i_] = *(const short8*)(rA_ + 4096 + i_ * 1024); \
    if (DOSTAGE) { STAGE1B((J) + 3); } \
    SBAR(); \
    __builtin_amdgcn_s_setprio(1); \
    MFMA16(acc, 4, av, bv); \
    __builtin_amdgcn_s_setprio(0); \
    TRAIL; \
}

__global__ __launch_bounds__(512, 2) void gemm1_kernel(const unsigned short* __restrict__ A,
                                                       const unsigned short* __restrict__ Bt,
                                                       const float* __restrict__ bias,
                                                       unsigned short* __restrict__ u_bf,
                                                       unsigned short* __restrict__ zs) {
    __shared__ __align__(16) unsigned short lds[4][2][8192];   // 128 KB: [slot][A/B][256*32]
    const int K = D_MODEL;

    int t = threadIdx.x;
    int lane = t & 63;
    int wave = t >> 6;
    int wm = wave >> 2;          // 0..1
    int wn = wave & 3;           // 0..3

    // bijective XCD swizzle: 256 blocks, XCD x owns m-blocks [4x, 4x+4), all n
    int bid = blockIdx.x;
    int swz = (bid & 7) * 32 + (bid >> 3);
    int m0 = (swz >> 3) * 256;
    int n0 = (swz & 7) * 256;

    // staging source (inverse-swizzled): lane covers (row=sub*16+srow, k=sk..sk+7)
    int srow = lane >> 2;
    int sk = ((lane & 3) * 8) ^ ((lane & 32) >> 1);
    const unsigned short* pA0 = A  + (size_t)(m0 + wave * 16 + srow) * K + sk;   // round 0: subs 0..7
    const unsigned short* pA1 = pA0 + (size_t)128 * K;                           // round 1: subs 8..15
    const unsigned short* pB0 = Bt + (size_t)(n0 + wave * 16 + srow) * K + sk;
    const unsigned short* pB1 = pB0 + (size_t)128 * K;

    // staging dests (wave-uniform, linear)
    unsigned short* dA0 = &lds[0][0][wave * 512];
    unsigned short* dA1 = &lds[0][0][(8 + wave) * 512];
    unsigned short* dB0 = &lds[0][1][wave * 512];
    unsigned short* dB1 = &lds[0][1][(8 + wave) * 512];

    // swizzled ds_read base: row=lane&15 within subtile, k-chunk=(lane>>4)*8
    int off_base = (lane & 15) * 64 + (((lane >> 4) * 16) ^ ((lane & 8) * 4));
    const char* ldsA_rd = (const char*)(&lds[0][0][0]) + wm * 8192 + off_base;
    const char* ldsB_rd = (const char*)(&lds[0][1][0]) + wn * 4096 + off_base;

    f32x4 acc[8][4] = {};

    // prologue: stage T0,T1,T2 (12 loads); drain T0 (keep 8 in flight)
    STAGE1A(0); STAGE1B(0); STAGE1A(1); STAGE1B(1); STAGE1A(2); STAGE1B(2);
    GATE(8);

    // main loop: 32 K-tiles; stage T(j+3); gate leaves newest 8 (2 tiles) in flight
    #pragma unroll 1
    for (int j = 0; j < 29; ++j) { G1_TILE(j, true, GATE(8)); }
    // peeled tail: staging done; shrink gates
    G1_TILE(29, false, GATE(4));
    G1_TILE(30, false, GATE(0));
    G1_TILE(31, false, (void)0);

    // epilogue: C/D layout col = lane&15, row = quad*4 + reg
    int col = lane & 15;
    int quad = lane >> 4;
    #pragma unroll
    for (int jf = 0; jf < 4; ++jf) {
        int n = n0 + wn * 64 + jf * 16 + col;
        float bs = bias[n];
        bool isU = (n < D_MODEL);            // uniform per block (n0 multiple of 256)
        #pragma unroll
        for (int i = 0; i < 8; ++i) {
            #pragma unroll
            for (int r = 0; r < 4; ++r) {
                int m = m0 + wm * 128 + i * 16 + quad * 4 + r;
                float v = acc[i][jf][r] + bs;
                if (isU) {
                    u_bf[(size_t)m * D_MODEL + n] = f2bf(v);
                } else {
                    float sv = v / (1.0f + __expf(-v));
                    zs[(size_t)m * D_MODEL + (n - D_MODEL)] = f2bf(sv);
                }
            }
        }
    }
}

// ============================================================================
// GEMM2: 128x256 tile, BK=32, 4 LDS slots (24KB each), lead-3 pipeline.
// 8 waves (2m x 4n), wave tile 64x64, acc[4][4]. Grid 64x4 = 256 blocks.
// ============================================================================
#define STAGE2(J) { size_t ko_ = (size_t)(J) * 32; int so_ = ((J) & 3) * 12288; \
    gload16(pA0 + ko_, dA + so_); gload16(pB0 + ko_, dB0 + so_); gload16(pB1 + ko_, dB1 + so_); }

#define G2_TILE(J, DOSTAGE, TRAIL) { \
    const int slot_ = (J) & 3; \
    const char* rA_ = ldsA_rd + slot_ * 24576; \
    const char* rB_ = ldsB_rd + slot_ * 24576; \
    short8 av[4], bv[4]; \
    _Pragma("unroll") for (int i_ = 0; i_ < 4; ++i_) av[i_] = *(const short8*)(rA_ + i_ * 1024); \
    _Pragma("unroll") for (int j_ = 0; j_ < 4; ++j_) bv[j_] = *(const short8*)(rB_ + j_ * 1024); \
    if (DOSTAGE) { STAGE2((J) + 3); } \
    SBAR(); \
    __builtin_amdgcn_s_setprio(1); \
    MFMA16(acc, 0, av, bv); \
    __builtin_amdgcn_s_setprio(0); \
    TRAIL; \
}

__global__ __launch_bounds__(512, 2) void gemm2_kernel(const unsigned short* __restrict__ A,
                                                       const unsigned short* __restrict__ Bt,
                                                       const float* __restrict__ bias,
                                                       float* __restrict__ out_f,
                                                       const float* __restrict__ resid) {
    __shared__ __align__(16) unsigned short lds[4][12288];   // 96 KB: [slot][A 4096 | B 8192]
    const int K = D_MODEL;

    int t = threadIdx.x;
    int lane = t & 63;
    int wave = t >> 6;
    int wm = wave >> 2;          // 0..1
    int wn = wave & 3;           // 0..3

    // XCD swizzle: XCD x owns m-blocks [8x, 8x+8), all 4 n-blocks (A 2MB + B 2MB ~ L2)
    int bid = blockIdx.x;
    int swz = (bid & 7) * 32 + (bid >> 3);
    int m0 = (swz >> 2) * 128;
    int n0 = (swz & 3) * 256;

    int srow = lane >> 2;
    int sk = ((lane & 3) * 8) ^ ((lane & 32) >> 1);
    const unsigned short* pA0 = A  + (size_t)(m0 + wave * 16 + srow) * K + sk;   // 8 subtiles, 1 round
    const unsigned short* pB0 = Bt + (size_t)(n0 + wave * 16 + srow) * K + sk;   // 16 subtiles, 2 rounds
    const unsigned short* pB1 = pB0 + (size_t)128 * K;

    unsigned short* dA  = &lds[0][wave * 512];
    unsigned short* dB0 = &lds[0][4096 + wave * 512];
    unsigned short* dB1 = &lds[0][8192 + wave * 512];

    int off_base = (lane & 15) * 64 + (((lane >> 4) * 16) ^ ((lane & 8) * 4));
    const char* ldsA_rd = (const char*)(&lds[0][0]) + wm * 4096 + off_base;
    const char* ldsB_rd = (const char*)(&lds[0][0]) + 8192 + wn * 4096 + off_base;

    f32x4 acc[4][4] = {};

    STAGE2(0); STAGE2(1); STAGE2(2);   // 9 loads; drain T0 (keep 6)
    GATE(6);

    #pragma unroll 1
    for (int j = 0; j < 29; ++j) { G2_TILE(j, true, GATE(6)); }
    G2_TILE(29, false, GATE(3));
    G2_TILE(30, false, GATE(0));
    G2_TILE(31, false, (void)0);

    int col = lane & 15;
    int quad = lane >> 4;
    #pragma unroll
    for (int jf = 0; jf < 4; ++jf) {
        int n = n0 + wn * 64 + jf * 16 + col;
        float bs = bias[n];
        #pragma unroll
        for (int i = 0; i < 4; ++i) {
            #pragma unroll
            for (int r = 0; r < 4; ++r) {
                int m = m0 + wm * 64 + i * 16 + quad * 4 + r;
                float y = acc[i][jf][r] + bs + resid[(size_t)m * D_MODEL + n];
                y = fminf(10.0f, fmaxf(-10.0f, y));
                out_f[(size_t)m * D_MODEL + n] = y;
            }
        }
    }
}

// ---------------- chunked SSM scan (u bf16) ----------------
static __device__ __forceinline__ void load_params(const float* __restrict__ A_log,
                                                   const float* __restrict__ log_dt,
                                                   int d, float* ab, float& dt_out) {
    float dt = fminf(1.0f, fmaxf(1e-4f, __expf(log_dt[d])));
    #pragma unroll
    for (int n = 0; n < D_STATE; n++) {
        float a = __expf(-__expf(A_log[d * D_STATE + n]) * dt);
        ab[n] = fminf(1.0f - 1e-8f, fmaxf(1e-8f, a));
    }
    dt_out = dt;
}

// pass1: zero-init local scan of each chunk; writes chunk-final states.
__global__ __launch_bounds__(256) void scan1_kernel(const unsigned short* __restrict__ u,
                                                    const float* __restrict__ A_log,
                                                    const float* __restrict__ log_dt,
                                                    float* __restrict__ s_local) {
    int gid = blockIdx.x * 256 + threadIdx.x;
    int d = gid & (D_MODEL - 1);
    int c = (gid >> 10) & (N_CHUNK - 1);
    int b = gid >> 15;

    float ab[D_STATE], dt;
    load_params(A_log, log_dt, d, ab, dt);

    float s[D_STATE];
    #pragma unroll
    for (int n = 0; n < D_STATE; n++) s[n] = 0.0f;

    const unsigned short* up = u + ((size_t)(b * L_SEQ + c * C_LEN)) * D_MODEL + d;
    for (int t = 0; t < C_LEN; t++) {
        float uv = bf2f(up[(size_t)t * D_MODEL]);
        #pragma unroll
        for (int n = 0; n < D_STATE; n++) s[n] = fmaf(ab[n], s[n], uv);
    }
    float* sl = s_local + ((size_t)(b * N_CHUNK + c) * D_STATE) * D_MODEL + d;
    #pragma unroll
    for (int n = 0; n < D_STATE; n++) sl[(size_t)n * D_MODEL] = s[n];
}

// combine: sequential prefix over chunks.
__global__ __launch_bounds__(256) void scan_combine_kernel(const float* __restrict__ s_local,
                                                           const float* __restrict__ A_log,
                                                           const float* __restrict__ log_dt,
                                                           float* __restrict__ s_init) {
    int gid = blockIdx.x * 256 + threadIdx.x;
    int d = gid & (D_MODEL - 1);
    int n = (gid >> 10) & (D_STATE - 1);
    int b = gid >> 14;

    float dt = fminf(1.0f, fmaxf(1e-4f, __expf(log_dt[d])));
    float a = __expf(-__expf(A_log[d * D_STATE + n]) * dt);
    a = fminf(1.0f - 1e-8f, fmaxf(1e-8f, a));
    float aP = a;
    #pragma unroll
    for (int q = 0; q < 6; q++) aP = aP * aP;   // a^64

    float s = 0.0f;
    size_t stride_c = (size_t)D_STATE * D_MODEL;
    const float* sl = s_local + ((size_t)b * N_CHUNK * D_STATE + n) * D_MODEL + d;
    float* si = s_init + ((size_t)b * N_CHUNK * D_STATE + n) * D_MODEL + d;
    si[0] = 0.0f;
    for (int c = 1; c < N_CHUNK; c++) {
        s = fmaf(aP, s, sl[(size_t)(c - 1) * stride_c]);
        si[(size_t)c * stride_c] = s;
    }
}

// pass2: rescan with correct init; fuse y = sum_n cb_n s_n, y *= silu(z); bf16 out.
__global__ __launch_bounds__(256) void scan2_kernel(const unsigned short* __restrict__ u,
                                                    const unsigned short* __restrict__ zs,
                                                    const float* __restrict__ A_log,
                                                    const float* __restrict__ Bp,
                                                    const float* __restrict__ Cp,
                                                    const float* __restrict__ log_dt,
                                                    const float* __restrict__ s_init,
                                                    unsigned short* __restrict__ yz) {
    int gid = blockIdx.x * 256 + threadIdx.x;
    int d = gid & (D_MODEL - 1);
    int c = (gid >> 10) & (N_CHUNK - 1);
    int b = gid >> 15;

    float ab[D_STATE], dt;
    load_params(A_log, log_dt, d, ab, dt);
    float cb[D_STATE];
    #pragma unroll
    for (int n = 0; n < D_STATE; n++)
        cb[n] = Cp[d * D_STATE + n] * Bp[d * D_STATE + n] * dt;

    float s[D_STATE];
    const float* si = s_init + ((size_t)(b * N_CHUNK + c) * D_STATE) * D_MODEL + d;
    #pragma unroll
    for (int n = 0; n < D_STATE; n++) s[n] = si[(size_t)n * D_MODEL];

    size_t m0 = (size_t)(b * L_SEQ + c * C_LEN);
    const unsigned short* up = u + m0 * D_MODEL + d;
    const unsigned short* zp = zs + m0 * D_MODEL + d;
    unsigned short* yp = yz + m0 * D_MODEL + d;

    for (int t = 0; t < C_LEN; t++) {
        float uv = bf2f(up[(size_t)t * D_MODEL]);
        #pragma unroll
        for (int n = 0; n < D_STATE; n++) s[n] = fmaf(ab[n], s[n], uv);
        float y = 0.0f;
        #pragma unroll
        for (int n = 0; n < D_STATE; n++) y = fmaf(cb[n], s[n], y);
        float zv = bf2f(zp[(size_t)t * D_MODEL]);
        yp[(size_t)t * D_MODEL] = f2bf(y * zv);
    }
}

extern "C" void kernel_launch(void* const* d_in, const int* in_sizes, int n_in,
                              void* d_out, int out_size, void* d_ws, size_t ws_size,
                              hipStream_t stream) {
    const float* x       = (const float*)d_in[0];
    const float* A_log   = (const float*)d_in[1];
    const float* B_param = (const float*)d_in[2];
    const float* C_param = (const float*)d_in[3];
    const float* log_dt  = (const float*)d_in[4];
    const float* in_w    = (const float*)d_in[5];
    const float* in_b    = (const float*)d_in[6];
    const float* out_w   = (const float*)d_in[7];
    const float* out_b   = (const float*)d_in[8];
    const float* ln_g    = (const float*)d_in[9];
    const float* ln_b    = (const float*)d_in[10];
    float* out = (float*)d_out;

    char* ws = (char*)d_ws;
    size_t off = 0;
    unsigned short* xn = (unsigned short*)(ws + off); off += (size_t)M_ROWS * D_MODEL * 2;        // 16 MB
    unsigned short* w1 = (unsigned short*)(ws + off); off += (size_t)2 * D_MODEL * D_MODEL * 2;   // 4 MB
    unsigned short* u  = (unsigned short*)(ws + off); off += (size_t)M_ROWS * D_MODEL * 2;        // 16 MB
    unsigned short* zs = (unsigned short*)(ws + off); off += (size_t)M_ROWS * D_MODEL * 2;        // 16 MB
    unsigned short* yz = (unsigned short*)(ws + off); off += (size_t)M_ROWS * D_MODEL * 2;        // 16 MB
    unsigned short* w2 = (unsigned short*)(ws + off); off += (size_t)D_MODEL * D_MODEL * 2;       // 2 MB
    float* s_local = (float*)(ws + off); off += (size_t)B_SZ * N_CHUNK * D_STATE * D_MODEL * 4;   // 8 MB
    float* s_init  = (float*)(ws + off); off += (size_t)B_SZ * N_CHUNK * D_STATE * D_MODEL * 4;   // 8 MB

    // weights -> bf16
    {
        int n4 = 2 * D_MODEL * D_MODEL / 4;
        conv_bf16_kernel<<<(n4 + 255) / 256, 256, 0, stream>>>(in_w, w1, n4);
    }
    {
        int n4 = D_MODEL * D_MODEL / 4;
        conv_bf16_kernel<<<(n4 + 255) / 256, 256, 0, stream>>>(out_w, w2, n4);
    }

    // layernorm
    ln_kernel<<<M_ROWS, 256, 0, stream>>>(x, ln_g, ln_b, xn);

    // GEMM1: (8192x1024) @ (2048x1024)^T -> u bf16 / silu(z) bf16
    gemm1_kernel<<<256, 512, 0, stream>>>(xn, w1, in_b, u, zs);

    // chunked SSM scan
    scan1_kernel<<<(B_SZ * N_CHUNK * D_MODEL) / 256, 256, 0, stream>>>(u, A_log, log_dt, s_local);
    scan_combine_kernel<<<(B_SZ * D_STATE * D_MODEL) / 256, 256, 0, stream>>>(s_local, A_log, log_dt, s_init);
    scan2_kernel<<<(B_SZ * N_CHUNK * D_MODEL) / 256, 256, 0, stream>>>(
        u, zs, A_log, B_param, C_param, log_dt, s_init, yz);

    // GEMM2: (8192x1024) @ (1024x1024)^T + resid, clip
    gemm2_kernel<<<256, 512, 0, stream>>>(yz, w2, out_b, out, x);
}

// Round 2
// 210.089 us; speedup vs baseline: 1.0241x; 1.0201x over previous
//
#include <hip/hip_runtime.h>
#include <hip/hip_bf16.h>

#define D_MODEL 1024
#define D_STATE 16
#define L_SEQ 2048
#define B_SZ 4
#define M_ROWS (B_SZ * L_SEQ)   // 8192
#define N_CHUNK 32               // chunks per sequence
#define C_LEN 64                 // timesteps per chunk (32*64 = 2048)

typedef __attribute__((ext_vector_type(8))) short short8;
typedef __attribute__((ext_vector_type(4))) float f32x4;

// Raw barrier (no waitcnt) and the per-K-tile gate: counted vmcnt (never 0 in
// steady state) + lgkm drain (WAR protection for the slot about to be staged).
#define SBAR()  asm volatile("s_barrier" ::: "memory")
#define GATE(N) asm volatile("s_waitcnt vmcnt(" #N ") lgkmcnt(0)\n\ts_barrier" ::: "memory")

typedef const unsigned short __attribute__((address_space(1))) gas_us;
typedef unsigned short __attribute__((address_space(3))) las_us;
static __device__ __forceinline__ void gload16(const unsigned short* g, unsigned short* l) {
    // global -> LDS DMA, 16B per lane, dest = wave-uniform base + lane*16
    __builtin_amdgcn_global_load_lds((gas_us*)g, (las_us*)l, 16, 0, 0);
}

static __device__ __forceinline__ unsigned short f2bf(float f) {
    unsigned int u = __float_as_uint(f);
    unsigned int r = (u + 0x7FFFu + ((u >> 16) & 1u)) >> 16;   // RNE
    return (unsigned short)r;
}
static __device__ __forceinline__ float bf2f(unsigned short u) {
    return __uint_as_float(((unsigned int)u) << 16);
}

// ---------------- fused prep: LN rows + weight bf16 conversion ----------------
// blocks [0,8192): LayerNorm row; [8192,10240): w1 conv; [10240,11264): w2 conv
__global__ __launch_bounds__(256) void prep_kernel(const float* __restrict__ x,
                                                   const float* __restrict__ g,
                                                   const float* __restrict__ b,
                                                   unsigned short* __restrict__ xn,
                                                   const float* __restrict__ in_w,
                                                   unsigned short* __restrict__ w1,
                                                   const float* __restrict__ out_w,
                                                   unsigned short* __restrict__ w2) {
    __shared__ float sbuf[8];
    int bid = blockIdx.x;
    int t = threadIdx.x;
    if (bid < M_ROWS) {
        int row = bid;
        const float4* xr = (const float4*)(x + (size_t)row * D_MODEL);
        float4 v = xr[t];
        float s  = v.x + v.y + v.z + v.w;
        float ss = v.x * v.x + v.y * v.y + v.z * v.z + v.w * v.w;
        #pragma unroll
        for (int o = 32; o > 0; o >>= 1) {
            s  += __shfl_down(s,  o);
            ss += __shfl_down(ss, o);
        }
        int wid = t >> 6;
        if ((t & 63) == 0) { sbuf[wid] = s; sbuf[4 + wid] = ss; }
        __syncthreads();
        float S  = sbuf[0] + sbuf[1] + sbuf[2] + sbuf[3];
        float SS = sbuf[4] + sbuf[5] + sbuf[6] + sbuf[7];
        float mu  = S * (1.0f / D_MODEL);
        float var = SS * (1.0f / D_MODEL) - mu * mu;
        float inv = rsqrtf(var + 1e-5f);
        float4 gv = ((const float4*)g)[t];
        float4 bv = ((const float4*)b)[t];
        ushort4 o;
        o.x = f2bf((v.x - mu) * inv * gv.x + bv.x);
        o.y = f2bf((v.y - mu) * inv * gv.y + bv.y);
        o.z = f2bf((v.z - mu) * inv * gv.z + bv.z);
        o.w = f2bf((v.w - mu) * inv * gv.w + bv.w);
        ((ushort4*)(xn + (size_t)row * D_MODEL))[t] = o;
    } else if (bid < M_ROWS + 2048) {
        int i = (bid - M_ROWS) * 256 + t;           // < 524288 exactly
        float4 v = ((const float4*)in_w)[i];
        ushort4 o;
        o.x = f2bf(v.x); o.y = f2bf(v.y); o.z = f2bf(v.z); o.w = f2bf(v.w);
        ((ushort4*)w1)[i] = o;
    } else {
        int i = (bid - M_ROWS - 2048) * 256 + t;    // < 262144 exactly
        float4 v = ((const float4*)out_w)[i];
        ushort4 o;
        o.x = f2bf(v.x); o.y = f2bf(v.y); o.z = f2bf(v.z); o.w = f2bf(v.w);
        ((ushort4*)w2)[i] = o;
    }
}

// 16 MFMA cluster: 4 m-frags x 4 n-frags
#define MFMA16(ACC, AV, BV) { \
    _Pragma("unroll") for (int i_ = 0; i_ < 4; ++i_) { \
        _Pragma("unroll") for (int jf_ = 0; jf_ < 4; ++jf_) \
            ACC[i_][jf_] = __builtin_amdgcn_mfma_f32_16x16x32_bf16( \
                AV[i_], BV[jf_], ACC[i_][jf_], 0, 0, 0); } }

// ============================================================================
// Shared GEMM machinery: 128x256 tile, BK=32, 4 LDS slots (24KB each), lead-3
// counted-vmcnt pipeline. 8 waves (2m x 4n), wave tile 64x64, acc[4][4].
// Per K-tile: read 8 frags, stage T(j+3) (3 gloads), SBAR, 16 MFMA, GATE(6).
// LDS per slot: A 8KB (8 subtiles of [16r][32k]) | B 16KB (16 subtiles).
// XOR swizzle: k ^= 16 elems when row&8; inverse-swizzled global src,
// swizzled ds_read (both-sides rule).
// ============================================================================
#define STAGE(J) { size_t ko_ = (size_t)(J) * 32; int so_ = ((J) & 3) * 12288; \
    gload16(pA0 + ko_, dA + so_); gload16(pB0 + ko_, dB0 + so_); gload16(pB1 + ko_, dB1 + so_); }

#define G_TILE(J, DOSTAGE, TRAIL) { \
    const int slot_ = (J) & 3; \
    const char* rA_ = ldsA_rd + slot_ * 24576; \
    const char* rB_ = ldsB_rd + slot_ * 24576; \
    short8 av[4], bv[4]; \
    _Pragma("unroll") for (int i_ = 0; i_ < 4; ++i_) av[i_] = *(const short8*)(rA_ + i_ * 1024); \
    _Pragma("unroll") for (int j_ = 0; j_ < 4; ++j_) bv[j_] = *(const short8*)(rB_ + j_ * 1024); \
    if (DOSTAGE) { STAGE((J) + 3); } \
    SBAR(); \
    __builtin_amdgcn_s_setprio(1); \
    MFMA16(acc, av, bv); \
    __builtin_amdgcn_s_setprio(0); \
    TRAIL; \
}

#define GEMM_PREAMBLE(APTR, BPTR, NWGM_SHIFT, NWGN_MASK, NBLK_PER_XCD) \
    const int K = D_MODEL; \
    int t = threadIdx.x; \
    int lane = t & 63; \
    int wave = t >> 6; \
    int wm = wave >> 2; \
    int wn = wave & 3; \
    int bid = blockIdx.x; \
    int swz = (bid & 7) * (NBLK_PER_XCD) + (bid >> 3); \
    int m0 = (swz >> (NWGM_SHIFT)) * 128; \
    int n0 = (swz & (NWGN_MASK)) * 256; \
    int srow = lane >> 2; \
    int sk = ((lane & 3) * 8) ^ ((lane & 32) >> 1); \
    const unsigned short* pA0 = (APTR) + (size_t)(m0 + wave * 16 + srow) * K + sk; \
    const unsigned short* pB0 = (BPTR) + (size_t)(n0 + wave * 16 + srow) * K + sk; \
    const unsigned short* pB1 = pB0 + (size_t)128 * K; \
    unsigned short* dA  = &lds[0][wave * 512]; \
    unsigned short* dB0 = &lds[0][4096 + wave * 512]; \
    unsigned short* dB1 = &lds[0][8192 + wave * 512]; \
    int off_base = (lane & 15) * 64 + (((lane >> 4) * 16) ^ ((lane & 8) * 4)); \
    const char* ldsA_rd = (const char*)(&lds[0][0]) + wm * 4096 + off_base; \
    const char* ldsB_rd = (const char*)(&lds[0][0]) + 8192 + wn * 4096 + off_base; \
    f32x4 acc[4][4] = {}; \
    STAGE(0); STAGE(1); STAGE(2); \
    GATE(6); \
    _Pragma("unroll 1") \
    for (int j = 0; j < 29; ++j) { G_TILE(j, true, GATE(6)); } \
    G_TILE(29, false, GATE(3)); \
    G_TILE(30, false, GATE(0)); \
    G_TILE(31, false, (void)0);

// GEMM1: (8192x1024) @ (2048x1024)^T -> u bf16 / silu(z) bf16. Grid 512.
__global__ __launch_bounds__(512, 2) void gemm1_kernel(const unsigned short* __restrict__ A,
                                                       const unsigned short* __restrict__ Bt,
                                                       const float* __restrict__ bias,
                                                       unsigned short* __restrict__ u_bf,
                                                       unsigned short* __restrict__ zs) {
    __shared__ __align__(16) unsigned short lds[4][12288];   // 96 KB
    GEMM_PREAMBLE(A, Bt, 3, 7, 64)

    // epilogue: row-major line completion. C/D: col=lane&15, row=quad*4+r
    int col = lane & 15;
    int quad = lane >> 4;
    float bs[4];
    #pragma unroll
    for (int jf = 0; jf < 4; ++jf) bs[jf] = bias[n0 + wn * 64 + jf * 16 + col];
    bool isU = (n0 < D_MODEL);               // uniform per block
    int nbase = isU ? (n0 + wn * 64 + col) : (n0 - D_MODEL + wn * 64 + col);
    unsigned short* obase = isU ? u_bf : zs;
    #pragma unroll
    for (int i = 0; i < 4; ++i) {
        #pragma unroll
        for (int r = 0; r < 4; ++r) {
            int m = m0 + wm * 64 + i * 16 + quad * 4 + r;
            unsigned short* orow = obase + (size_t)m * D_MODEL + nbase;
            #pragma unroll
            for (int jf = 0; jf < 4; ++jf) {
                float v = acc[i][jf][r] + bs[jf];
                if (!isU) v = v / (1.0f + __expf(-v));
                orow[jf * 16] = f2bf(v);
            }
        }
    }
}

// GEMM2: (8192x1024) @ (1024x1024)^T + resid, clip. Grid 256.
__global__ __launch_bounds__(512, 2) void gemm2_kernel(const unsigned short* __restrict__ A,
                                                       const unsigned short* __restrict__ Bt,
                                                       const float* __restrict__ bias,
                                                       float* __restrict__ out_f,
                                                       const float* __restrict__ resid) {
    __shared__ __align__(16) unsigned short lds[4][12288];   // 96 KB
    GEMM_PREAMBLE(A, Bt, 2, 3, 32)

    int col = lane & 15;
    int quad = lane >> 4;
    float bs[4];
    #pragma unroll
    for (int jf = 0; jf < 4; ++jf) bs[jf] = bias[n0 + wn * 64 + jf * 16 + col];
    #pragma unroll
    for (int i = 0; i < 4; ++i) {
        #pragma unroll
        for (int r = 0; r < 4; ++r) {
            int m = m0 + wm * 64 + i * 16 + quad * 4 + r;
            const float* rrow = resid + (size_t)m * D_MODEL + n0 + wn * 64 + col;
            float* orow = out_f + (size_t)m * D_MODEL + n0 + wn * 64 + col;
            #pragma unroll
            for (int jf = 0; jf < 4; ++jf) {
                float y = acc[i][jf][r] + bs[jf] + rrow[jf * 16];
                y = fminf(10.0f, fmaxf(-10.0f, y));
                orow[jf * 16] = y;
            }
        }
    }
}

// ---------------- chunked SSM scan (u bf16) ----------------
static __device__ __forceinline__ void load_params(const float* __restrict__ A_log,
                                                   const float* __restrict__ log_dt,
                                                   int d, float* ab, float& dt_out) {
    float dt = fminf(1.0f, fmaxf(1e-4f, __expf(log_dt[d])));
    #pragma unroll
    for (int n = 0; n < D_STATE; n++) {
        float a = __expf(-__expf(A_log[d * D_STATE + n]) * dt);
        ab[n] = fminf(1.0f - 1e-8f, fmaxf(1e-8f, a));
    }
    dt_out = dt;
}

// pass1: zero-init local scan of each chunk; writes chunk-final states.
__global__ __launch_bounds__(256) void scan1_kernel(const unsigned short* __restrict__ u,
                                                    const float* __restrict__ A_log,
                                                    const float* __restrict__ log_dt,
                                                    float* __restrict__ s_local) {
    int gid = blockIdx.x * 256 + threadIdx.x;
    int d = gid & (D_MODEL - 1);
    int c = (gid >> 10) & (N_CHUNK - 1);
    int b = gid >> 15;

    float ab[D_STATE], dt;
    load_params(A_log, log_dt, d, ab, dt);

    float s[D_STATE];
    #pragma unroll
    for (int n = 0; n < D_STATE; n++) s[n] = 0.0f;

    const unsigned short* up = u + ((size_t)(b * L_SEQ + c * C_LEN)) * D_MODEL + d;
    for (int t = 0; t < C_LEN; t++) {
        float uv = bf2f(up[(size_t)t * D_MODEL]);
        #pragma unroll
        for (int n = 0; n < D_STATE; n++) s[n] = fmaf(ab[n], s[n], uv);
    }
    float* sl = s_local + ((size_t)(b * N_CHUNK + c) * D_STATE) * D_MODEL + d;
    #pragma unroll
    for (int n = 0; n < D_STATE; n++) sl[(size_t)n * D_MODEL] = s[n];
}

// combine: sequential prefix over chunks.
__global__ __launch_bounds__(256) void scan_combine_kernel(const float* __restrict__ s_local,
                                                           const float* __restrict__ A_log,
                                                           const float* __restrict__ log_dt,
                                                           float* __restrict__ s_init) {
    int gid = blockIdx.x * 256 + threadIdx.x;
    int d = gid & (D_MODEL - 1);
    int n = (gid >> 10) & (D_STATE - 1);
    int b = gid >> 14;

    float dt = fminf(1.0f, fmaxf(1e-4f, __expf(log_dt[d])));
    float a = __expf(-__expf(A_log[d * D_STATE + n]) * dt);
    a = fminf(1.0f - 1e-8f, fmaxf(1e-8f, a));
    float aP = a;
    #pragma unroll
    for (int q = 0; q < 6; q++) aP = aP * aP;   // a^64

    float s = 0.0f;
    size_t stride_c = (size_t)D_STATE * D_MODEL;
    const float* sl = s_local + ((size_t)b * N_CHUNK * D_STATE + n) * D_MODEL + d;
    float* si = s_init + ((size_t)b * N_CHUNK * D_STATE + n) * D_MODEL + d;
    si[0] = 0.0f;
    for (int c = 1; c < N_CHUNK; c++) {
        s = fmaf(aP, s, sl[(size_t)(c - 1) * stride_c]);
        si[(size_t)c * stride_c] = s;
    }
}

// pass2: rescan with correct init; fuse y = sum_n cb_n s_n, y *= silu(z); bf16 out.
__global__ __launch_bounds__(256) void scan2_kernel(const unsigned short* __restrict__ u,
                                                    const unsigned short* __restrict__ zs,
                                                    const float* __restrict__ A_log,
                                                    const float* __restrict__ Bp,
                                                    const float* __restrict__ Cp,
                                                    const float* __restrict__ log_dt,
                                                    const float* __restrict__ s_init,
                                                    unsigned short* __restrict__ yz) {
    int gid = blockIdx.x * 256 + threadIdx.x;
    int d = gid & (D_MODEL - 1);
    int c = (gid >> 10) & (N_CHUNK - 1);
    int b = gid >> 15;

    float ab[D_STATE], dt;
    load_params(A_log, log_dt, d, ab, dt);
    float cb[D_STATE];
    #pragma unroll
    for (int n = 0; n < D_STATE; n++)
        cb[n] = Cp[d * D_STATE + n] * Bp[d * D_STATE + n] * dt;

    float s[D_STATE];
    const float* si = s_init + ((size_t)(b * N_CHUNK + c) * D_STATE) * D_MODEL + d;
    #pragma unroll
    for (int n = 0; n < D_STATE; n++) s[n] = si[(size_t)n * D_MODEL];

    size_t m0 = (size_t)(b * L_SEQ + c * C_LEN);
    const unsigned short* up = u + m0 * D_MODEL + d;
    const unsigned short* zp = zs + m0 * D_MODEL + d;
    unsigned short* yp = yz + m0 * D_MODEL + d;

    for (int t = 0; t < C_LEN; t++) {
        float uv = bf2f(up[(size_t)t * D_MODEL]);
        #pragma unroll
        for (int n = 0; n < D_STATE; n++) s[n] = fmaf(ab[n], s[n], uv);
        float y = 0.0f;
        #pragma unroll
        for (int n = 0; n < D_STATE; n++) y = fmaf(cb[n], s[n], y);
        float zv = bf2f(zp[(size_t)t * D_MODEL]);
        yp[(size_t)t * D_MODEL] = f2bf(y * zv);
    }
}

extern "C" void kernel_launch(void* const* d_in, const int* in_sizes, int n_in,
                              void* d_out, int out_size, void* d_ws, size_t ws_size,
                              hipStream_t stream) {
    const float* x       = (const float*)d_in[0];
    const float* A_log   = (const float*)d_in[1];
    const float* B_param = (const float*)d_in[2];
    const float* C_param = (const float*)d_in[3];
    const float* log_dt  = (const float*)d_in[4];
    const float* in_w    = (const float*)d_in[5];
    const float* in_b    = (const float*)d_in[6];
    const float* out_w   = (const float*)d_in[7];
    const float* out_b   = (const float*)d_in[8];
    const float* ln_g    = (const float*)d_in[9];
    const float* ln_b    = (const float*)d_in[10];
    float* out = (float*)d_out;

    char* ws = (char*)d_ws;
    size_t off = 0;
    unsigned short* xn = (unsigned short*)(ws + off); off += (size_t)M_ROWS * D_MODEL * 2;        // 16 MB
    unsigned short* w1 = (unsigned short*)(ws + off); off += (size_t)2 * D_MODEL * D_MODEL * 2;   // 4 MB
    unsigned short* u  = (unsigned short*)(ws + off); off += (size_t)M_ROWS * D_MODEL * 2;        // 16 MB
    unsigned short* zs = (unsigned short*)(ws + off); off += (size_t)M_ROWS * D_MODEL * 2;        // 16 MB
    unsigned short* yz = (unsigned short*)(ws + off); off += (size_t)M_ROWS * D_MODEL * 2;        // 16 MB
    unsigned short* w2 = (unsigned short*)(ws + off); off += (size_t)D_MODEL * D_MODEL * 2;       // 2 MB
    float* s_local = (float*)(ws + off); off += (size_t)B_SZ * N_CHUNK * D_STATE * D_MODEL * 4;   // 8 MB
    float* s_init  = (float*)(ws + off); off += (size_t)B_SZ * N_CHUNK * D_STATE * D_MODEL * 4;   // 8 MB

    // fused LN + weight conversion (1 launch instead of 3)
    prep_kernel<<<M_ROWS + 2048 + 1024, 256, 0, stream>>>(x, ln_g, ln_b, xn, in_w, w1, out_w, w2);

    // GEMM1: (8192x1024) @ (2048x1024)^T -> u bf16 / silu(z) bf16
    gemm1_kernel<<<512, 512, 0, stream>>>(xn, w1, in_b, u, zs);

    // chunked SSM scan
    scan1_kernel<<<(B_SZ * N_CHUNK * D_MODEL) / 256, 256, 0, stream>>>(u, A_log, log_dt, s_local);
    scan_combine_kernel<<<(B_SZ * D_STATE * D_MODEL) / 256, 256, 0, stream>>>(s_local, A_log, log_dt, s_init);
    scan2_kernel<<<(B_SZ * N_CHUNK * D_MODEL) / 256, 256, 0, stream>>>(
        u, zs, A_log, B_param, C_param, log_dt, s_init, yz);

    // GEMM2: (8192x1024) @ (1024x1024)^T + resid, clip
    gemm2_kernel<<<256, 512, 0, stream>>>(yz, w2, out_b, out, x);
}

// Round 3
// 206.095 us; speedup vs baseline: 1.0440x; 1.0194x over previous
//
#include <hip/hip_runtime.h>
#include <hip/hip_bf16.h>

#define D_MODEL 1024
#define D_STATE 16
#define L_SEQ 2048
#define B_SZ 4
#define M_ROWS (B_SZ * L_SEQ)   // 8192
#define N_CHUNK 32               // chunks per sequence
#define C_LEN 64                 // timesteps per chunk (32*64 = 2048)

typedef __attribute__((ext_vector_type(8))) short short8;
typedef __attribute__((ext_vector_type(4))) float f32x4;

// Raw barrier (no waitcnt) and the per-K-tile gate: counted vmcnt (never 0 in
// steady state) + lgkm drain before the barrier (all waves' LDS reads done ->
// staging into the retiring slot is WAR-safe).
#define SBAR()  asm volatile("s_barrier" ::: "memory")
#define GATE(N) asm volatile("s_waitcnt vmcnt(" #N ") lgkmcnt(0)\n\ts_barrier" ::: "memory")

typedef const unsigned short __attribute__((address_space(1))) gas_us;
typedef unsigned short __attribute__((address_space(3))) las_us;
static __device__ __forceinline__ void gload16(const unsigned short* g, unsigned short* l) {
    // global -> LDS DMA, 16B per lane, dest = wave-uniform base + lane*16
    __builtin_amdgcn_global_load_lds((gas_us*)g, (las_us*)l, 16, 0, 0);
}

static __device__ __forceinline__ unsigned short f2bf(float f) {
    unsigned int u = __float_as_uint(f);
    unsigned int r = (u + 0x7FFFu + ((u >> 16) & 1u)) >> 16;   // RNE
    return (unsigned short)r;
}
static __device__ __forceinline__ float bf2f(unsigned short u) {
    return __uint_as_float(((unsigned int)u) << 16);
}

// ---------------- fused prep: LN rows + weight bf16 conversion ----------------
__global__ __launch_bounds__(256) void prep_kernel(const float* __restrict__ x,
                                                   const float* __restrict__ g,
                                                   const float* __restrict__ b,
                                                   unsigned short* __restrict__ xn,
                                                   const float* __restrict__ in_w,
                                                   unsigned short* __restrict__ w1,
                                                   const float* __restrict__ out_w,
                                                   unsigned short* __restrict__ w2) {
    __shared__ float sbuf[8];
    int bid = blockIdx.x;
    int t = threadIdx.x;
    if (bid < M_ROWS) {
        int row = bid;
        const float4* xr = (const float4*)(x + (size_t)row * D_MODEL);
        float4 v = xr[t];
        float s  = v.x + v.y + v.z + v.w;
        float ss = v.x * v.x + v.y * v.y + v.z * v.z + v.w * v.w;
        #pragma unroll
        for (int o = 32; o > 0; o >>= 1) {
            s  += __shfl_down(s,  o);
            ss += __shfl_down(ss, o);
        }
        int wid = t >> 6;
        if ((t & 63) == 0) { sbuf[wid] = s; sbuf[4 + wid] = ss; }
        __syncthreads();
        float S  = sbuf[0] + sbuf[1] + sbuf[2] + sbuf[3];
        float SS = sbuf[4] + sbuf[5] + sbuf[6] + sbuf[7];
        float mu  = S * (1.0f / D_MODEL);
        float var = SS * (1.0f / D_MODEL) - mu * mu;
        float inv = rsqrtf(var + 1e-5f);
        float4 gv = ((const float4*)g)[t];
        float4 bv = ((const float4*)b)[t];
        ushort4 o;
        o.x = f2bf((v.x - mu) * inv * gv.x + bv.x);
        o.y = f2bf((v.y - mu) * inv * gv.y + bv.y);
        o.z = f2bf((v.z - mu) * inv * gv.z + bv.z);
        o.w = f2bf((v.w - mu) * inv * gv.w + bv.w);
        ((ushort4*)(xn + (size_t)row * D_MODEL))[t] = o;
    } else if (bid < M_ROWS + 2048) {
        int i = (bid - M_ROWS) * 256 + t;
        float4 v = ((const float4*)in_w)[i];
        ushort4 o;
        o.x = f2bf(v.x); o.y = f2bf(v.y); o.z = f2bf(v.z); o.w = f2bf(v.w);
        ((ushort4*)w1)[i] = o;
    } else {
        int i = (bid - M_ROWS - 2048) * 256 + t;
        float4 v = ((const float4*)out_w)[i];
        ushort4 o;
        o.x = f2bf(v.x); o.y = f2bf(v.y); o.z = f2bf(v.z); o.w = f2bf(v.w);
        ((ushort4*)w2)[i] = o;
    }
}

// ============================================================================
// GEMM1: 256x256 tile, BK=32, 4 LDS slots (32KB each = 128KB), lead-3
// counted-vmcnt pipeline. 8 waves (2m x 4n), wave tile 128x64, acc[8][4].
// Per K-tile: read 12 frags (av[8], bv[4]), stage T(j+3) (4 gloads), SBAR,
// 32 MFMA (setprio), GATE(8). Same control flow as the proven 128x256
// pipeline, scaled: halves barrier density per MFMA, cuts LDS bytes/FLOP 1.33x.
// LDS per slot: A 16KB (16 subtiles of [16r][32k], 1KB each) | B 16KB.
// XOR swizzle: k ^= 16 elems when row&8; inverse-swizzled global src,
// swizzled ds_read (both-sides rule).
// ============================================================================
#define MFMA32(ACC, AV, BV) { \
    _Pragma("unroll") for (int i_ = 0; i_ < 8; ++i_) { \
        _Pragma("unroll") for (int jf_ = 0; jf_ < 4; ++jf_) \
            ACC[i_][jf_] = __builtin_amdgcn_mfma_f32_16x16x32_bf16( \
                AV[i_], BV[jf_], ACC[i_][jf_], 0, 0, 0); } }

#define STAGE1(J) { size_t ko_ = (size_t)(J) * 32; int so_ = ((J) & 3) * 16384; \
    gload16(pA0 + ko_, dA0 + so_); gload16(pA1 + ko_, dA1 + so_); \
    gload16(pB0 + ko_, dB0 + so_); gload16(pB1 + ko_, dB1 + so_); }

#define G1_TILE(J, DOSTAGE, TRAIL) { \
    const int slot_ = (J) & 3; \
    const char* rA_ = ldsA_rd + slot_ * 32768; \
    const char* rB_ = ldsB_rd + slot_ * 32768; \
    short8 av[8], bv[4]; \
    _Pragma("unroll") for (int i_ = 0; i_ < 8; ++i_) av[i_] = *(const short8*)(rA_ + i_ * 1024); \
    _Pragma("unroll") for (int j_ = 0; j_ < 4; ++j_) bv[j_] = *(const short8*)(rB_ + j_ * 1024); \
    if (DOSTAGE) { STAGE1((J) + 3); } \
    SBAR(); \
    __builtin_amdgcn_s_setprio(1); \
    MFMA32(acc, av, bv); \
    __builtin_amdgcn_s_setprio(0); \
    TRAIL; \
}

__global__ __launch_bounds__(512, 1) void gemm1_kernel(const unsigned short* __restrict__ A,
                                                       const unsigned short* __restrict__ Bt,
                                                       const float* __restrict__ bias,
                                                       unsigned short* __restrict__ u_bf,
                                                       unsigned short* __restrict__ zs) {
    __shared__ __align__(16) unsigned short lds[4][16384];   // 128 KB
    const int K = D_MODEL;

    int t = threadIdx.x;
    int lane = t & 63;
    int wave = t >> 6;
    int wm = wave >> 2;          // 0..1 -> A half (128 rows)
    int wn = wave & 3;           // 0..3 -> B quarter (64 rows)

    // XCD swizzle: 256 blocks = 32m x 8n; XCD x owns m-panels [4x,4x+4), all n
    int bid = blockIdx.x;
    int swz = (bid & 7) * 32 + (bid >> 3);
    int m0 = (swz >> 3) * 256;
    int n0 = (swz & 7) * 256;

    // staging source (inverse-swizzled): lane -> (row = sub*16 + (lane>>2), k)
    int srow = lane >> 2;
    int sk = ((lane & 3) * 8) ^ ((lane & 32) >> 1);
    const unsigned short* pA0 = A  + (size_t)(m0 + wave * 16 + srow) * K + sk;   // subtiles 0..7
    const unsigned short* pA1 = pA0 + (size_t)128 * K;                           // subtiles 8..15
    const unsigned short* pB0 = Bt + (size_t)(n0 + wave * 16 + srow) * K + sk;
    const unsigned short* pB1 = pB0 + (size_t)128 * K;

    // staging dests (wave-uniform, linear; shorts)
    unsigned short* dA0 = &lds[0][wave * 512];
    unsigned short* dA1 = &lds[0][4096 + wave * 512];
    unsigned short* dB0 = &lds[0][8192 + wave * 512];
    unsigned short* dB1 = &lds[0][12288 + wave * 512];

    // swizzled ds_read base (bytes)
    int off_base = (lane & 15) * 64 + (((lane >> 4) * 16) ^ ((lane & 8) * 4));
    const char* ldsA_rd = (const char*)(&lds[0][0]) + wm * 8192 + off_base;
    const char* ldsB_rd = (const char*)(&lds[0][0]) + 16384 + wn * 4096 + off_base;

    f32x4 acc[8][4] = {};

    // prologue: stage T0..T2 (12 loads); GATE(8) -> T0 landed
    STAGE1(0); STAGE1(1); STAGE1(2);
    GATE(8);

    #pragma unroll 1
    for (int j = 0; j < 29; ++j) { G1_TILE(j, true, GATE(8)); }
    G1_TILE(29, false, GATE(4));
    G1_TILE(30, false, GATE(0));
    G1_TILE(31, false, (void)0);

    // epilogue: row-major line completion. C/D: col=lane&15, row=quad*4+r
    int col = lane & 15;
    int quad = lane >> 4;
    float bs[4];
    #pragma unroll
    for (int jf = 0; jf < 4; ++jf) bs[jf] = bias[n0 + wn * 64 + jf * 16 + col];
    bool isU = (n0 < D_MODEL);               // uniform per block
    int nbase = isU ? (n0 + wn * 64 + col) : (n0 - D_MODEL + wn * 64 + col);
    unsigned short* obase = isU ? u_bf : zs;
    #pragma unroll
    for (int i = 0; i < 8; ++i) {
        #pragma unroll
        for (int r = 0; r < 4; ++r) {
            int m = m0 + wm * 128 + i * 16 + quad * 4 + r;
            unsigned short* orow = obase + (size_t)m * D_MODEL + nbase;
            #pragma unroll
            for (int jf = 0; jf < 4; ++jf) {
                float v = acc[i][jf][r] + bs[jf];
                if (!isU) v = v / (1.0f + __expf(-v));
                orow[jf * 16] = f2bf(v);
            }
        }
    }
}

// ============================================================================
// GEMM2: 128x256 tile, BK=32, 4 LDS slots (24KB each), lead-3 pipeline.
// Proven machinery from R2 — unchanged.
// ============================================================================
#define MFMA16(ACC, AV, BV) { \
    _Pragma("unroll") for (int i_ = 0; i_ < 4; ++i_) { \
        _Pragma("unroll") for (int jf_ = 0; jf_ < 4; ++jf_) \
            ACC[i_][jf_] = __builtin_amdgcn_mfma_f32_16x16x32_bf16( \
                AV[i_], BV[jf_], ACC[i_][jf_], 0, 0, 0); } }

#define STAGE2(J) { size_t ko_ = (size_t)(J) * 32; int so_ = ((J) & 3) * 12288; \
    gload16(pA0 + ko_, dA + so_); gload16(pB0 + ko_, dB0 + so_); gload16(pB1 + ko_, dB1 + so_); }

#define G2_TILE(J, DOSTAGE, TRAIL) { \
    const int slot_ = (J) & 3; \
    const char* rA_ = ldsA_rd + slot_ * 24576; \
    const char* rB_ = ldsB_rd + slot_ * 24576; \
    short8 av[4], bv[4]; \
    _Pragma("unroll") for (int i_ = 0; i_ < 4; ++i_) av[i_] = *(const short8*)(rA_ + i_ * 1024); \
    _Pragma("unroll") for (int j_ = 0; j_ < 4; ++j_) bv[j_] = *(const short8*)(rB_ + j_ * 1024); \
    if (DOSTAGE) { STAGE2((J) + 3); } \
    SBAR(); \
    __builtin_amdgcn_s_setprio(1); \
    MFMA16(acc, av, bv); \
    __builtin_amdgcn_s_setprio(0); \
    TRAIL; \
}

__global__ __launch_bounds__(512, 2) void gemm2_kernel(const unsigned short* __restrict__ A,
                                                       const unsigned short* __restrict__ Bt,
                                                       const float* __restrict__ bias,
                                                       float* __restrict__ out_f,
                                                       const float* __restrict__ resid) {
    __shared__ __align__(16) unsigned short lds[4][12288];   // 96 KB
    const int K = D_MODEL;

    int t = threadIdx.x;
    int lane = t & 63;
    int wave = t >> 6;
    int wm = wave >> 2;
    int wn = wave & 3;

    int bid = blockIdx.x;
    int swz = (bid & 7) * 32 + (bid >> 3);
    int m0 = (swz >> 2) * 128;
    int n0 = (swz & 3) * 256;

    int srow = lane >> 2;
    int sk = ((lane & 3) * 8) ^ ((lane & 32) >> 1);
    const unsigned short* pA0 = A  + (size_t)(m0 + wave * 16 + srow) * K + sk;
    const unsigned short* pB0 = Bt + (size_t)(n0 + wave * 16 + srow) * K + sk;
    const unsigned short* pB1 = pB0 + (size_t)128 * K;

    unsigned short* dA  = &lds[0][wave * 512];
    unsigned short* dB0 = &lds[0][4096 + wave * 512];
    unsigned short* dB1 = &lds[0][8192 + wave * 512];

    int off_base = (lane & 15) * 64 + (((lane >> 4) * 16) ^ ((lane & 8) * 4));
    const char* ldsA_rd = (const char*)(&lds[0][0]) + wm * 4096 + off_base;
    const char* ldsB_rd = (const char*)(&lds[0][0]) + 8192 + wn * 4096 + off_base;

    f32x4 acc[4][4] = {};

    STAGE2(0); STAGE2(1); STAGE2(2);
    GATE(6);

    #pragma unroll 1
    for (int j = 0; j < 29; ++j) { G2_TILE(j, true, GATE(6)); }
    G2_TILE(29, false, GATE(3));
    G2_TILE(30, false, GATE(0));
    G2_TILE(31, false, (void)0);

    int col = lane & 15;
    int quad = lane >> 4;
    float bs[4];
    #pragma unroll
    for (int jf = 0; jf < 4; ++jf) bs[jf] = bias[n0 + wn * 64 + jf * 16 + col];
    #pragma unroll
    for (int i = 0; i < 4; ++i) {
        #pragma unroll
        for (int r = 0; r < 4; ++r) {
            int m = m0 + wm * 64 + i * 16 + quad * 4 + r;
            const float* rrow = resid + (size_t)m * D_MODEL + n0 + wn * 64 + col;
            float* orow = out_f + (size_t)m * D_MODEL + n0 + wn * 64 + col;
            #pragma unroll
            for (int jf = 0; jf < 4; ++jf) {
                float y = acc[i][jf][r] + bs[jf] + rrow[jf * 16];
                y = fminf(10.0f, fmaxf(-10.0f, y));
                orow[jf * 16] = y;
            }
        }
    }
}

// ---------------- chunked SSM scan (u bf16) ----------------
static __device__ __forceinline__ void load_params(const float* __restrict__ A_log,
                                                   const float* __restrict__ log_dt,
                                                   int d, float* ab, float& dt_out) {
    float dt = fminf(1.0f, fmaxf(1e-4f, __expf(log_dt[d])));
    #pragma unroll
    for (int n = 0; n < D_STATE; n++) {
        float a = __expf(-__expf(A_log[d * D_STATE + n]) * dt);
        ab[n] = fminf(1.0f - 1e-8f, fmaxf(1e-8f, a));
    }
    dt_out = dt;
}

// pass1: zero-init local scan of each chunk; writes chunk-final states.
__global__ __launch_bounds__(256) void scan1_kernel(const unsigned short* __restrict__ u,
                                                    const float* __restrict__ A_log,
                                                    const float* __restrict__ log_dt,
                                                    float* __restrict__ s_local) {
    int gid = blockIdx.x * 256 + threadIdx.x;
    int d = gid & (D_MODEL - 1);
    int c = (gid >> 10) & (N_CHUNK - 1);
    int b = gid >> 15;

    float ab[D_STATE], dt;
    load_params(A_log, log_dt, d, ab, dt);

    float s[D_STATE];
    #pragma unroll
    for (int n = 0; n < D_STATE; n++) s[n] = 0.0f;

    const unsigned short* up = u + ((size_t)(b * L_SEQ + c * C_LEN)) * D_MODEL + d;
    for (int t = 0; t < C_LEN; t++) {
        float uv = bf2f(up[(size_t)t * D_MODEL]);
        #pragma unroll
        for (int n = 0; n < D_STATE; n++) s[n] = fmaf(ab[n], s[n], uv);
    }
    float* sl = s_local + ((size_t)(b * N_CHUNK + c) * D_STATE) * D_MODEL + d;
    #pragma unroll
    for (int n = 0; n < D_STATE; n++) sl[(size_t)n * D_MODEL] = s[n];
}

// combine: sequential prefix over chunks.
__global__ __launch_bounds__(256) void scan_combine_kernel(const float* __restrict__ s_local,
                                                           const float* __restrict__ A_log,
                                                           const float* __restrict__ log_dt,
                                                           float* __restrict__ s_init) {
    int gid = blockIdx.x * 256 + threadIdx.x;
    int d = gid & (D_MODEL - 1);
    int n = (gid >> 10) & (D_STATE - 1);
    int b = gid >> 14;

    float dt = fminf(1.0f, fmaxf(1e-4f, __expf(log_dt[d])));
    float a = __expf(-__expf(A_log[d * D_STATE + n]) * dt);
    a = fminf(1.0f - 1e-8f, fmaxf(1e-8f, a));
    float aP = a;
    #pragma unroll
    for (int q = 0; q < 6; q++) aP = aP * aP;   // a^64

    float s = 0.0f;
    size_t stride_c = (size_t)D_STATE * D_MODEL;
    const float* sl = s_local + ((size_t)b * N_CHUNK * D_STATE + n) * D_MODEL + d;
    float* si = s_init + ((size_t)b * N_CHUNK * D_STATE + n) * D_MODEL + d;
    si[0] = 0.0f;
    for (int c = 1; c < N_CHUNK; c++) {
        s = fmaf(aP, s, sl[(size_t)(c - 1) * stride_c]);
        si[(size_t)c * stride_c] = s;
    }
}

// pass2: rescan with correct init; fuse y = sum_n cb_n s_n, y *= silu(z); bf16 out.
__global__ __launch_bounds__(256) void scan2_kernel(const unsigned short* __restrict__ u,
                                                    const unsigned short* __restrict__ zs,
                                                    const float* __restrict__ A_log,
                                                    const float* __restrict__ Bp,
                                                    const float* __restrict__ Cp,
                                                    const float* __restrict__ log_dt,
                                                    const float* __restrict__ s_init,
                                                    unsigned short* __restrict__ yz) {
    int gid = blockIdx.x * 256 + threadIdx.x;
    int d = gid & (D_MODEL - 1);
    int c = (gid >> 10) & (N_CHUNK - 1);
    int b = gid >> 15;

    float ab[D_STATE], dt;
    load_params(A_log, log_dt, d, ab, dt);
    float cb[D_STATE];
    #pragma unroll
    for (int n = 0; n < D_STATE; n++)
        cb[n] = Cp[d * D_STATE + n] * Bp[d * D_STATE + n] * dt;

    float s[D_STATE];
    const float* si = s_init + ((size_t)(b * N_CHUNK + c) * D_STATE) * D_MODEL + d;
    #pragma unroll
    for (int n = 0; n < D_STATE; n++) s[n] = si[(size_t)n * D_MODEL];

    size_t m0 = (size_t)(b * L_SEQ + c * C_LEN);
    const unsigned short* up = u + m0 * D_MODEL + d;
    const unsigned short* zp = zs + m0 * D_MODEL + d;
    unsigned short* yp = yz + m0 * D_MODEL + d;

    for (int t = 0; t < C_LEN; t++) {
        float uv = bf2f(up[(size_t)t * D_MODEL]);
        #pragma unroll
        for (int n = 0; n < D_STATE; n++) s[n] = fmaf(ab[n], s[n], uv);
        float y = 0.0f;
        #pragma unroll
        for (int n = 0; n < D_STATE; n++) y = fmaf(cb[n], s[n], y);
        float zv = bf2f(zp[(size_t)t * D_MODEL]);
        yp[(size_t)t * D_MODEL] = f2bf(y * zv);
    }
}

extern "C" void kernel_launch(void* const* d_in, const int* in_sizes, int n_in,
                              void* d_out, int out_size, void* d_ws, size_t ws_size,
                              hipStream_t stream) {
    const float* x       = (const float*)d_in[0];
    const float* A_log   = (const float*)d_in[1];
    const float* B_param = (const float*)d_in[2];
    const float* C_param = (const float*)d_in[3];
    const float* log_dt  = (const float*)d_in[4];
    const float* in_w    = (const float*)d_in[5];
    const float* in_b    = (const float*)d_in[6];
    const float* out_w   = (const float*)d_in[7];
    const float* out_b   = (const float*)d_in[8];
    const float* ln_g    = (const float*)d_in[9];
    const float* ln_b    = (const float*)d_in[10];
    float* out = (float*)d_out;

    char* ws = (char*)d_ws;
    size_t off = 0;
    unsigned short* xn = (unsigned short*)(ws + off); off += (size_t)M_ROWS * D_MODEL * 2;        // 16 MB
    unsigned short* w1 = (unsigned short*)(ws + off); off += (size_t)2 * D_MODEL * D_MODEL * 2;   // 4 MB
    unsigned short* u  = (unsigned short*)(ws + off); off += (size_t)M_ROWS * D_MODEL * 2;        // 16 MB
    unsigned short* zs = (unsigned short*)(ws + off); off += (size_t)M_ROWS * D_MODEL * 2;        // 16 MB
    unsigned short* yz = (unsigned short*)(ws + off); off += (size_t)M_ROWS * D_MODEL * 2;        // 16 MB
    unsigned short* w2 = (unsigned short*)(ws + off); off += (size_t)D_MODEL * D_MODEL * 2;       // 2 MB
    float* s_local = (float*)(ws + off); off += (size_t)B_SZ * N_CHUNK * D_STATE * D_MODEL * 4;   // 8 MB
    float* s_init  = (float*)(ws + off); off += (size_t)B_SZ * N_CHUNK * D_STATE * D_MODEL * 4;   // 8 MB

    // fused LN + weight conversion
    prep_kernel<<<M_ROWS + 2048 + 1024, 256, 0, stream>>>(x, ln_g, ln_b, xn, in_w, w1, out_w, w2);

    // GEMM1: (8192x1024) @ (2048x1024)^T -> u bf16 / silu(z) bf16
    gemm1_kernel<<<256, 512, 0, stream>>>(xn, w1, in_b, u, zs);

    // chunked SSM scan
    scan1_kernel<<<(B_SZ * N_CHUNK * D_MODEL) / 256, 256, 0, stream>>>(u, A_log, log_dt, s_local);
    scan_combine_kernel<<<(B_SZ * D_STATE * D_MODEL) / 256, 256, 0, stream>>>(s_local, A_log, log_dt, s_init);
    scan2_kernel<<<(B_SZ * N_CHUNK * D_MODEL) / 256, 256, 0, stream>>>(
        u, zs, A_log, B_param, C_param, log_dt, s_init, yz);

    // GEMM2: (8192x1024) @ (1024x1024)^T + resid, clip
    gemm2_kernel<<<256, 512, 0, stream>>>(yz, w2, out_b, out, x);
}

// Round 4
// 198.101 us; speedup vs baseline: 1.0861x; 1.0404x over previous
//
#include <hip/hip_runtime.h>
#include <hip/hip_bf16.h>

#define D_MODEL 1024
#define D_STATE 16
#define L_SEQ 2048
#define B_SZ 4
#define M_ROWS (B_SZ * L_SEQ)   // 8192
#define N_CHUNK 32               // chunks per sequence
#define C_LEN 64                 // timesteps per chunk (32*64 = 2048)

typedef __attribute__((ext_vector_type(8))) short short8;
typedef __attribute__((ext_vector_type(4))) float f32x4;

// Raw barrier (no waitcnt) and the per-K-tile gate: counted vmcnt (never 0 in
// steady state) + lgkm drain before the barrier (all waves' LDS reads done ->
// staging into the retiring slot is WAR-safe).
#define SBAR()  asm volatile("s_barrier" ::: "memory")
#define GATE(N) asm volatile("s_waitcnt vmcnt(" #N ") lgkmcnt(0)\n\ts_barrier" ::: "memory")

typedef const unsigned short __attribute__((address_space(1))) gas_us;
typedef unsigned short __attribute__((address_space(3))) las_us;
static __device__ __forceinline__ void gload16(const unsigned short* g, unsigned short* l) {
    // global -> LDS DMA, 16B per lane, dest = wave-uniform base + lane*16
    __builtin_amdgcn_global_load_lds((gas_us*)g, (las_us*)l, 16, 0, 0);
}

static __device__ __forceinline__ unsigned short f2bf(float f) {
    unsigned int u = __float_as_uint(f);
    unsigned int r = (u + 0x7FFFu + ((u >> 16) & 1u)) >> 16;   // RNE
    return (unsigned short)r;
}
static __device__ __forceinline__ float bf2f(unsigned short u) {
    return __uint_as_float(((unsigned int)u) << 16);
}

// ---------------- fused prep: LN rows + weight bf16 conversion ----------------
__global__ __launch_bounds__(256) void prep_kernel(const float* __restrict__ x,
                                                   const float* __restrict__ g,
                                                   const float* __restrict__ b,
                                                   unsigned short* __restrict__ xn,
                                                   const float* __restrict__ in_w,
                                                   unsigned short* __restrict__ w1,
                                                   const float* __restrict__ out_w,
                                                   unsigned short* __restrict__ w2) {
    __shared__ float sbuf[8];
    int bid = blockIdx.x;
    int t = threadIdx.x;
    if (bid < M_ROWS) {
        int row = bid;
        const float4* xr = (const float4*)(x + (size_t)row * D_MODEL);
        float4 v = xr[t];
        float s  = v.x + v.y + v.z + v.w;
        float ss = v.x * v.x + v.y * v.y + v.z * v.z + v.w * v.w;
        #pragma unroll
        for (int o = 32; o > 0; o >>= 1) {
            s  += __shfl_down(s,  o);
            ss += __shfl_down(ss, o);
        }
        int wid = t >> 6;
        if ((t & 63) == 0) { sbuf[wid] = s; sbuf[4 + wid] = ss; }
        __syncthreads();
        float S  = sbuf[0] + sbuf[1] + sbuf[2] + sbuf[3];
        float SS = sbuf[4] + sbuf[5] + sbuf[6] + sbuf[7];
        float mu  = S * (1.0f / D_MODEL);
        float var = SS * (1.0f / D_MODEL) - mu * mu;
        float inv = rsqrtf(var + 1e-5f);
        float4 gv = ((const float4*)g)[t];
        float4 bv = ((const float4*)b)[t];
        ushort4 o;
        o.x = f2bf((v.x - mu) * inv * gv.x + bv.x);
        o.y = f2bf((v.y - mu) * inv * gv.y + bv.y);
        o.z = f2bf((v.z - mu) * inv * gv.z + bv.z);
        o.w = f2bf((v.w - mu) * inv * gv.w + bv.w);
        ((ushort4*)(xn + (size_t)row * D_MODEL))[t] = o;
    } else if (bid < M_ROWS + 2048) {
        int i = (bid - M_ROWS) * 256 + t;
        float4 v = ((const float4*)in_w)[i];
        ushort4 o;
        o.x = f2bf(v.x); o.y = f2bf(v.y); o.z = f2bf(v.z); o.w = f2bf(v.w);
        ((ushort4*)w1)[i] = o;
    } else {
        int i = (bid - M_ROWS - 2048) * 256 + t;
        float4 v = ((const float4*)out_w)[i];
        ushort4 o;
        o.x = f2bf(v.x); o.y = f2bf(v.y); o.z = f2bf(v.z); o.w = f2bf(v.w);
        ((ushort4*)w2)[i] = o;
    }
}

// ============================================================================
// GEMM1: 256x256 tile, BK=32, 4 LDS slots (32KB each = 128KB), lead-3
// counted-vmcnt pipeline. 8 waves (2m x 4n), wave tile 128x64, acc[8][4].
// ============================================================================
#define MFMA32(ACC, AV, BV) { \
    _Pragma("unroll") for (int i_ = 0; i_ < 8; ++i_) { \
        _Pragma("unroll") for (int jf_ = 0; jf_ < 4; ++jf_) \
            ACC[i_][jf_] = __builtin_amdgcn_mfma_f32_16x16x32_bf16( \
                AV[i_], BV[jf_], ACC[i_][jf_], 0, 0, 0); } }

#define STAGE1(J) { size_t ko_ = (size_t)(J) * 32; int so_ = ((J) & 3) * 16384; \
    gload16(pA0 + ko_, dA0 + so_); gload16(pA1 + ko_, dA1 + so_); \
    gload16(pB0 + ko_, dB0 + so_); gload16(pB1 + ko_, dB1 + so_); }

#define G1_TILE(J, DOSTAGE, TRAIL) { \
    const int slot_ = (J) & 3; \
    const char* rA_ = ldsA_rd + slot_ * 32768; \
    const char* rB_ = ldsB_rd + slot_ * 32768; \
    short8 av[8], bv[4]; \
    _Pragma("unroll") for (int i_ = 0; i_ < 8; ++i_) av[i_] = *(const short8*)(rA_ + i_ * 1024); \
    _Pragma("unroll") for (int j_ = 0; j_ < 4; ++j_) bv[j_] = *(const short8*)(rB_ + j_ * 1024); \
    if (DOSTAGE) { STAGE1((J) + 3); } \
    SBAR(); \
    __builtin_amdgcn_s_setprio(1); \
    MFMA32(acc, av, bv); \
    __builtin_amdgcn_s_setprio(0); \
    TRAIL; \
}

__global__ __launch_bounds__(512, 1) void gemm1_kernel(const unsigned short* __restrict__ A,
                                                       const unsigned short* __restrict__ Bt,
                                                       const float* __restrict__ bias,
                                                       unsigned short* __restrict__ u_bf,
                                                       unsigned short* __restrict__ zs) {
    __shared__ __align__(16) unsigned short lds[4][16384];   // 128 KB
    const int K = D_MODEL;

    int t = threadIdx.x;
    int lane = t & 63;
    int wave = t >> 6;
    int wm = wave >> 2;          // 0..1 -> A half (128 rows)
    int wn = wave & 3;           // 0..3 -> B quarter (64 rows)

    int bid = blockIdx.x;
    int swz = (bid & 7) * 32 + (bid >> 3);
    int m0 = (swz >> 3) * 256;
    int n0 = (swz & 7) * 256;

    int srow = lane >> 2;
    int sk = ((lane & 3) * 8) ^ ((lane & 32) >> 1);
    const unsigned short* pA0 = A  + (size_t)(m0 + wave * 16 + srow) * K + sk;   // subtiles 0..7
    const unsigned short* pA1 = pA0 + (size_t)128 * K;                           // subtiles 8..15
    const unsigned short* pB0 = Bt + (size_t)(n0 + wave * 16 + srow) * K + sk;
    const unsigned short* pB1 = pB0 + (size_t)128 * K;

    unsigned short* dA0 = &lds[0][wave * 512];
    unsigned short* dA1 = &lds[0][4096 + wave * 512];
    unsigned short* dB0 = &lds[0][8192 + wave * 512];
    unsigned short* dB1 = &lds[0][12288 + wave * 512];

    int off_base = (lane & 15) * 64 + (((lane >> 4) * 16) ^ ((lane & 8) * 4));
    const char* ldsA_rd = (const char*)(&lds[0][0]) + wm * 8192 + off_base;
    const char* ldsB_rd = (const char*)(&lds[0][0]) + 16384 + wn * 4096 + off_base;

    f32x4 acc[8][4] = {};

    STAGE1(0); STAGE1(1); STAGE1(2);
    GATE(8);

    #pragma unroll 1
    for (int j = 0; j < 29; ++j) { G1_TILE(j, true, GATE(8)); }
    G1_TILE(29, false, GATE(4));
    G1_TILE(30, false, GATE(0));
    G1_TILE(31, false, (void)0);

    int col = lane & 15;
    int quad = lane >> 4;
    float bs[4];
    #pragma unroll
    for (int jf = 0; jf < 4; ++jf) bs[jf] = bias[n0 + wn * 64 + jf * 16 + col];
    bool isU = (n0 < D_MODEL);               // uniform per block
    int nbase = isU ? (n0 + wn * 64 + col) : (n0 - D_MODEL + wn * 64 + col);
    unsigned short* obase = isU ? u_bf : zs;
    #pragma unroll
    for (int i = 0; i < 8; ++i) {
        #pragma unroll
        for (int r = 0; r < 4; ++r) {
            int m = m0 + wm * 128 + i * 16 + quad * 4 + r;
            unsigned short* orow = obase + (size_t)m * D_MODEL + nbase;
            #pragma unroll
            for (int jf = 0; jf < 4; ++jf) {
                float v = acc[i][jf][r] + bs[jf];
                if (!isU) v = v / (1.0f + __expf(-v));
                orow[jf * 16] = f2bf(v);
            }
        }
    }
}

// ============================================================================
// GEMM2: 128x256 tile, BK=32, 4 LDS slots (24KB each), lead-3 pipeline.
// ============================================================================
#define MFMA16(ACC, AV, BV) { \
    _Pragma("unroll") for (int i_ = 0; i_ < 4; ++i_) { \
        _Pragma("unroll") for (int jf_ = 0; jf_ < 4; ++jf_) \
            ACC[i_][jf_] = __builtin_amdgcn_mfma_f32_16x16x32_bf16( \
                AV[i_], BV[jf_], ACC[i_][jf_], 0, 0, 0); } }

#define STAGE2(J) { size_t ko_ = (size_t)(J) * 32; int so_ = ((J) & 3) * 12288; \
    gload16(pA0 + ko_, dA + so_); gload16(pB0 + ko_, dB0 + so_); gload16(pB1 + ko_, dB1 + so_); }

#define G2_TILE(J, DOSTAGE, TRAIL) { \
    const int slot_ = (J) & 3; \
    const char* rA_ = ldsA_rd + slot_ * 24576; \
    const char* rB_ = ldsB_rd + slot_ * 24576; \
    short8 av[4], bv[4]; \
    _Pragma("unroll") for (int i_ = 0; i_ < 4; ++i_) av[i_] = *(const short8*)(rA_ + i_ * 1024); \
    _Pragma("unroll") for (int j_ = 0; j_ < 4; ++j_) bv[j_] = *(const short8*)(rB_ + j_ * 1024); \
    if (DOSTAGE) { STAGE2((J) + 3); } \
    SBAR(); \
    __builtin_amdgcn_s_setprio(1); \
    MFMA16(acc, av, bv); \
    __builtin_amdgcn_s_setprio(0); \
    TRAIL; \
}

__global__ __launch_bounds__(512, 2) void gemm2_kernel(const unsigned short* __restrict__ A,
                                                       const unsigned short* __restrict__ Bt,
                                                       const float* __restrict__ bias,
                                                       float* __restrict__ out_f,
                                                       const float* __restrict__ resid) {
    __shared__ __align__(16) unsigned short lds[4][12288];   // 96 KB
    const int K = D_MODEL;

    int t = threadIdx.x;
    int lane = t & 63;
    int wave = t >> 6;
    int wm = wave >> 2;
    int wn = wave & 3;

    int bid = blockIdx.x;
    int swz = (bid & 7) * 32 + (bid >> 3);
    int m0 = (swz >> 2) * 128;
    int n0 = (swz & 3) * 256;

    int srow = lane >> 2;
    int sk = ((lane & 3) * 8) ^ ((lane & 32) >> 1);
    const unsigned short* pA0 = A  + (size_t)(m0 + wave * 16 + srow) * K + sk;
    const unsigned short* pB0 = Bt + (size_t)(n0 + wave * 16 + srow) * K + sk;
    const unsigned short* pB1 = pB0 + (size_t)128 * K;

    unsigned short* dA  = &lds[0][wave * 512];
    unsigned short* dB0 = &lds[0][4096 + wave * 512];
    unsigned short* dB1 = &lds[0][8192 + wave * 512];

    int off_base = (lane & 15) * 64 + (((lane >> 4) * 16) ^ ((lane & 8) * 4));
    const char* ldsA_rd = (const char*)(&lds[0][0]) + wm * 4096 + off_base;
    const char* ldsB_rd = (const char*)(&lds[0][0]) + 8192 + wn * 4096 + off_base;

    f32x4 acc[4][4] = {};

    STAGE2(0); STAGE2(1); STAGE2(2);
    GATE(6);

    #pragma unroll 1
    for (int j = 0; j < 29; ++j) { G2_TILE(j, true, GATE(6)); }
    G2_TILE(29, false, GATE(3));
    G2_TILE(30, false, GATE(0));
    G2_TILE(31, false, (void)0);

    int col = lane & 15;
    int quad = lane >> 4;
    float bs[4];
    #pragma unroll
    for (int jf = 0; jf < 4; ++jf) bs[jf] = bias[n0 + wn * 64 + jf * 16 + col];
    #pragma unroll
    for (int i = 0; i < 4; ++i) {
        #pragma unroll
        for (int r = 0; r < 4; ++r) {
            int m = m0 + wm * 64 + i * 16 + quad * 4 + r;
            const float* rrow = resid + (size_t)m * D_MODEL + n0 + wn * 64 + col;
            float* orow = out_f + (size_t)m * D_MODEL + n0 + wn * 64 + col;
            #pragma unroll
            for (int jf = 0; jf < 4; ++jf) {
                float y = acc[i][jf][r] + bs[jf] + rrow[jf * 16];
                y = fminf(10.0f, fmaxf(-10.0f, y));
                orow[jf * 16] = y;
            }
        }
    }
}

// ============================================================================
// Fused SSM scan: one kernel replaces scan1 + combine + scan2.
// Block = 512 threads = 32 chunks x 16 d's; grid 256 = 4 b x 64 d-groups.
// Each thread: (1) local scan of its chunk (u cached in 32 VGPRs, fully
// unrolled so the cache stays in registers), (2) publish chunk-final state to
// LDS, (3) 5-step Hillis-Steele prefix over chunks (coefficient aP = a^64 is
// uniform across chunks, so constant-coefficient scan is valid), (4) rescan
// with correct init, fuse y = dot(cb,s) * silu-gated z, write bf16.
// Traffic: u 16MB + zs 16MB + yz 16MB = 48MB (was ~96MB over 3 kernels).
// XCD-chunked block swizzle: logical l = (bid&7)*32 + (bid>>3) puts the 4
// sibling d-groups sharing each 128B line on one XCD's L2.
// ============================================================================
__global__ __launch_bounds__(512) void scan_fused_kernel(const unsigned short* __restrict__ u,
                                                         const unsigned short* __restrict__ zs,
                                                         const float* __restrict__ A_log,
                                                         const float* __restrict__ Bp,
                                                         const float* __restrict__ Cp,
                                                         const float* __restrict__ log_dt,
                                                         unsigned short* __restrict__ yz) {
    __shared__ float S[N_CHUNK][D_STATE][17];   // 34,816 B; pad 17 vs bank aliasing

    int bid = blockIdx.x;
    int l  = (bid & 7) * 32 + (bid >> 3);   // bijective XCD-chunk swizzle
    int b  = l >> 6;                         // 0..3
    int dg = l & 63;                         // 0..63
    int t  = threadIdx.x;
    int c  = t >> 4;                         // chunk 0..31
    int dl = t & 15;
    int d  = dg * 16 + dl;

    // params
    float dt = fminf(1.0f, fmaxf(1e-4f, __expf(log_dt[d])));
    float ab[D_STATE];
    #pragma unroll
    for (int n = 0; n < D_STATE; n++) {
        float a = __expf(-__expf(A_log[d * D_STATE + n]) * dt);
        ab[n] = fminf(1.0f - 1e-8f, fmaxf(1e-8f, a));
    }

    // ---- pass 1: local chunk scan, cache u in registers ----
    size_t row0 = (size_t)(b * L_SEQ + c * C_LEN);
    const unsigned short* up = u + row0 * D_MODEL + d;

    unsigned int uc[32];          // 64 bf16 packed as 32 x u32
    float P[D_STATE];
    #pragma unroll
    for (int n = 0; n < D_STATE; n++) P[n] = 0.0f;
    #pragma unroll
    for (int tt = 0; tt < 32; tt++) {
        unsigned int lo = up[(size_t)(2 * tt) * D_MODEL];
        unsigned int hi = up[(size_t)(2 * tt + 1) * D_MODEL];
        uc[tt] = lo | (hi << 16);
        float u0 = __uint_as_float(lo << 16);
        float u1 = __uint_as_float(hi << 16);
        #pragma unroll
        for (int n = 0; n < D_STATE; n++) P[n] = fmaf(ab[n], P[n], u0);
        #pragma unroll
        for (int n = 0; n < D_STATE; n++) P[n] = fmaf(ab[n], P[n], u1);
    }

    // publish chunk-final states
    #pragma unroll
    for (int n = 0; n < D_STATE; n++) S[c][n][dl] = P[n];

    // aP = a^64 (uniform across chunks -> constant-coefficient prefix valid)
    float m[D_STATE];
    #pragma unroll
    for (int n = 0; n < D_STATE; n++) {
        float a2 = ab[n];
        #pragma unroll
        for (int q = 0; q < 6; q++) a2 = a2 * a2;
        m[n] = a2;
    }
    __syncthreads();

    // ---- Hillis-Steele inclusive prefix over c: P[c] += m * P[c-k] ----
    #pragma unroll
    for (int k = 1; k < N_CHUNK; k <<= 1) {
        float tmp[D_STATE];
        #pragma unroll
        for (int n = 0; n < D_STATE; n++) tmp[n] = (c >= k) ? S[c - k][n][dl] : 0.0f;
        __syncthreads();
        #pragma unroll
        for (int n = 0; n < D_STATE; n++) {
            P[n] = fmaf(m[n], tmp[n], P[n]);
            S[c][n][dl] = P[n];
        }
        #pragma unroll
        for (int n = 0; n < D_STATE; n++) m[n] = m[n] * m[n];
        __syncthreads();
    }

    // ---- pass 2: rescan with exclusive prefix init, fuse z-gate ----
    float s2[D_STATE];
    #pragma unroll
    for (int n = 0; n < D_STATE; n++) s2[n] = (c == 0) ? 0.0f : S[c - 1][n][dl];

    float cb[D_STATE];
    #pragma unroll
    for (int n = 0; n < D_STATE; n++)
        cb[n] = Cp[d * D_STATE + n] * Bp[d * D_STATE + n] * dt;

    const unsigned short* zp = zs + row0 * D_MODEL + d;
    unsigned short* yp = yz + row0 * D_MODEL + d;

    #pragma unroll
    for (int tt = 0; tt < 32; tt++) {
        unsigned int w = uc[tt];
        float u0 = __uint_as_float(w << 16);
        float u1 = __uint_as_float(w & 0xFFFF0000u);
        float y0 = 0.0f, y1 = 0.0f;
        #pragma unroll
        for (int n = 0; n < D_STATE; n++) s2[n] = fmaf(ab[n], s2[n], u0);
        #pragma unroll
        for (int n = 0; n < D_STATE; n++) y0 = fmaf(cb[n], s2[n], y0);
        #pragma unroll
        for (int n = 0; n < D_STATE; n++) s2[n] = fmaf(ab[n], s2[n], u1);
        #pragma unroll
        for (int n = 0; n < D_STATE; n++) y1 = fmaf(cb[n], s2[n], y1);
        float z0 = bf2f(zp[(size_t)(2 * tt) * D_MODEL]);
        float z1 = bf2f(zp[(size_t)(2 * tt + 1) * D_MODEL]);
        yp[(size_t)(2 * tt) * D_MODEL]     = f2bf(y0 * z0);
        yp[(size_t)(2 * tt + 1) * D_MODEL] = f2bf(y1 * z1);
    }
}

extern "C" void kernel_launch(void* const* d_in, const int* in_sizes, int n_in,
                              void* d_out, int out_size, void* d_ws, size_t ws_size,
                              hipStream_t stream) {
    const float* x       = (const float*)d_in[0];
    const float* A_log   = (const float*)d_in[1];
    const float* B_param = (const float*)d_in[2];
    const float* C_param = (const float*)d_in[3];
    const float* log_dt  = (const float*)d_in[4];
    const float* in_w    = (const float*)d_in[5];
    const float* in_b    = (const float*)d_in[6];
    const float* out_w   = (const float*)d_in[7];
    const float* out_b   = (const float*)d_in[8];
    const float* ln_g    = (const float*)d_in[9];
    const float* ln_b    = (const float*)d_in[10];
    float* out = (float*)d_out;

    char* ws = (char*)d_ws;
    size_t off = 0;
    unsigned short* xn = (unsigned short*)(ws + off); off += (size_t)M_ROWS * D_MODEL * 2;        // 16 MB
    unsigned short* w1 = (unsigned short*)(ws + off); off += (size_t)2 * D_MODEL * D_MODEL * 2;   // 4 MB
    unsigned short* u  = (unsigned short*)(ws + off); off += (size_t)M_ROWS * D_MODEL * 2;        // 16 MB
    unsigned short* zs = (unsigned short*)(ws + off); off += (size_t)M_ROWS * D_MODEL * 2;        // 16 MB
    unsigned short* yz = (unsigned short*)(ws + off); off += (size_t)M_ROWS * D_MODEL * 2;        // 16 MB
    unsigned short* w2 = (unsigned short*)(ws + off); off += (size_t)D_MODEL * D_MODEL * 2;       // 2 MB

    // fused LN + weight conversion
    prep_kernel<<<M_ROWS + 2048 + 1024, 256, 0, stream>>>(x, ln_g, ln_b, xn, in_w, w1, out_w, w2);

    // GEMM1: (8192x1024) @ (2048x1024)^T -> u bf16 / silu(z) bf16
    gemm1_kernel<<<256, 512, 0, stream>>>(xn, w1, in_b, u, zs);

    // fused chunked SSM scan (scan1 + combine + scan2 in one launch)
    scan_fused_kernel<<<256, 512, 0, stream>>>(u, zs, A_log, B_param, C_param, log_dt, yz);

    // GEMM2: (8192x1024) @ (1024x1024)^T + resid, clip
    gemm2_kernel<<<256, 512, 0, stream>>>(yz, w2, out_b, out, x);
}

// Round 5
// 193.770 us; speedup vs baseline: 1.1104x; 1.0224x over previous
//
#include <hip/hip_runtime.h>
#include <hip/hip_bf16.h>

#define D_MODEL 1024
#define D_STATE 16
#define L_SEQ 2048
#define B_SZ 4
#define M_ROWS (B_SZ * L_SEQ)   // 8192
#define N_CHUNK 32               // chunks per sequence
#define C_LEN 64                 // timesteps per chunk (32*64 = 2048)

typedef __attribute__((ext_vector_type(8))) short short8;
typedef __attribute__((ext_vector_type(4))) float f32x4;

// Raw barrier (no waitcnt) and the per-K-tile gate: counted vmcnt (never 0 in
// steady state) + lgkm drain before the barrier (all waves' LDS reads done ->
// staging into the retiring slot is WAR-safe).
#define SBAR()  asm volatile("s_barrier" ::: "memory")
#define GATE(N) asm volatile("s_waitcnt vmcnt(" #N ") lgkmcnt(0)\n\ts_barrier" ::: "memory")

typedef const unsigned short __attribute__((address_space(1))) gas_us;
typedef unsigned short __attribute__((address_space(3))) las_us;
static __device__ __forceinline__ void gload16(const unsigned short* g, unsigned short* l) {
    // global -> LDS DMA, 16B per lane, dest = wave-uniform base + lane*16
    __builtin_amdgcn_global_load_lds((gas_us*)g, (las_us*)l, 16, 0, 0);
}

static __device__ __forceinline__ unsigned short f2bf(float f) {
    unsigned int u = __float_as_uint(f);
    unsigned int r = (u + 0x7FFFu + ((u >> 16) & 1u)) >> 16;   // RNE
    return (unsigned short)r;
}
static __device__ __forceinline__ float bf2f(unsigned short u) {
    return __uint_as_float(((unsigned int)u) << 16);
}

// ---------------- fused prep: LN rows + weight bf16 conversion ----------------
__global__ __launch_bounds__(256) void prep_kernel(const float* __restrict__ x,
                                                   const float* __restrict__ g,
                                                   const float* __restrict__ b,
                                                   unsigned short* __restrict__ xn,
                                                   const float* __restrict__ in_w,
                                                   unsigned short* __restrict__ w1,
                                                   const float* __restrict__ out_w,
                                                   unsigned short* __restrict__ w2) {
    __shared__ float sbuf[8];
    int bid = blockIdx.x;
    int t = threadIdx.x;
    if (bid < M_ROWS) {
        int row = bid;
        const float4* xr = (const float4*)(x + (size_t)row * D_MODEL);
        float4 v = xr[t];
        float s  = v.x + v.y + v.z + v.w;
        float ss = v.x * v.x + v.y * v.y + v.z * v.z + v.w * v.w;
        #pragma unroll
        for (int o = 32; o > 0; o >>= 1) {
            s  += __shfl_down(s,  o);
            ss += __shfl_down(ss, o);
        }
        int wid = t >> 6;
        if ((t & 63) == 0) { sbuf[wid] = s; sbuf[4 + wid] = ss; }
        __syncthreads();
        float S  = sbuf[0] + sbuf[1] + sbuf[2] + sbuf[3];
        float SS = sbuf[4] + sbuf[5] + sbuf[6] + sbuf[7];
        float mu  = S * (1.0f / D_MODEL);
        float var = SS * (1.0f / D_MODEL) - mu * mu;
        float inv = rsqrtf(var + 1e-5f);
        float4 gv = ((const float4*)g)[t];
        float4 bv = ((const float4*)b)[t];
        ushort4 o;
        o.x = f2bf((v.x - mu) * inv * gv.x + bv.x);
        o.y = f2bf((v.y - mu) * inv * gv.y + bv.y);
        o.z = f2bf((v.z - mu) * inv * gv.z + bv.z);
        o.w = f2bf((v.w - mu) * inv * gv.w + bv.w);
        ((ushort4*)(xn + (size_t)row * D_MODEL))[t] = o;
    } else if (bid < M_ROWS + 2048) {
        int i = (bid - M_ROWS) * 256 + t;
        float4 v = ((const float4*)in_w)[i];
        ushort4 o;
        o.x = f2bf(v.x); o.y = f2bf(v.y); o.z = f2bf(v.z); o.w = f2bf(v.w);
        ((ushort4*)w1)[i] = o;
    } else {
        int i = (bid - M_ROWS - 2048) * 256 + t;
        float4 v = ((const float4*)out_w)[i];
        ushort4 o;
        o.x = f2bf(v.x); o.y = f2bf(v.y); o.z = f2bf(v.z); o.w = f2bf(v.w);
        ((ushort4*)w2)[i] = o;
    }
}

// 16 MFMA cluster: 4 m-frags x 4 n-frags
#define MFMA16(ACC, AV, BV) { \
    _Pragma("unroll") for (int i_ = 0; i_ < 4; ++i_) { \
        _Pragma("unroll") for (int jf_ = 0; jf_ < 4; ++jf_) \
            ACC[i_][jf_] = __builtin_amdgcn_mfma_f32_16x16x32_bf16( \
                AV[i_], BV[jf_], ACC[i_][jf_], 0, 0, 0); } }

// ============================================================================
// GEMM1: 128x256 tile, BK=32, 3 LDS slots (24KB each = 72KB) -> 2 blocks/CU
// co-resident (cross-block phase overlap fills the MFMA pipe while the other
// block is in its LDS/barrier phase). Lead-2 counted-vmcnt pipeline, GATE(3).
// 8 waves (2m x 4n), wave tile 64x64, acc[4][4]. Grid 512 = 2 blocks/CU.
// LDS per slot: A 8KB (8 subtiles [16r][32k], 1KB) | B 16KB (16 subtiles).
// XOR swizzle: k ^= 16 elems when row&8; inverse-swizzled global src,
// swizzled ds_read (both-sides rule).
// ============================================================================
__global__ __launch_bounds__(512, 4) void gemm1_kernel(const unsigned short* __restrict__ A,
                                                       const unsigned short* __restrict__ Bt,
                                                       const float* __restrict__ bias,
                                                       unsigned short* __restrict__ u_bf,
                                                       unsigned short* __restrict__ zs) {
    __shared__ __align__(16) unsigned short lds[3][12288];   // 72 KB
    const int K = D_MODEL;

    int t = threadIdx.x;
    int lane = t & 63;
    int wave = t >> 6;
    int wm = wave >> 2;          // 0..1 -> A half (64 rows each)
    int wn = wave & 3;           // 0..3 -> B quarter (64 rows)

    // bijective XCD swizzle: 512 blocks; XCD x owns swz [64x, 64x+64)
    int bid = blockIdx.x;
    int swz = (bid & 7) * 64 + (bid >> 3);
    int m0 = (swz >> 3) * 128;
    int n0 = (swz & 7) * 256;

    // staging source (inverse-swizzled): lane -> (row = sub*16 + (lane>>2), k)
    int srow = lane >> 2;
    int sk = ((lane & 3) * 8) ^ ((lane & 32) >> 1);
    const unsigned short* pA0 = A  + (size_t)(m0 + wave * 16 + srow) * K + sk;   // A subtiles 0..7
    const unsigned short* pB0 = Bt + (size_t)(n0 + wave * 16 + srow) * K + sk;   // B subtiles 0..7
    const unsigned short* pB1 = pB0 + (size_t)128 * K;                           // B subtiles 8..15

    // staging dests (wave-uniform, linear; shorts)
    unsigned short* dA  = &lds[0][0] + wave * 512;
    unsigned short* dB0 = &lds[0][0] + 4096 + wave * 512;
    unsigned short* dB1 = &lds[0][0] + 8192 + wave * 512;

    // swizzled ds_read base (bytes)
    int off_base = (lane & 15) * 64 + (((lane >> 4) * 16) ^ ((lane & 8) * 4));
    const char* ldsA_rd = (const char*)(&lds[0][0]) + wm * 4096 + off_base;
    const char* ldsB_rd = (const char*)(&lds[0][0]) + 8192 + wn * 4096 + off_base;

    f32x4 acc[4][4] = {};

    // prologue: T0 -> slot0, T1 -> slot1 (6 loads); GATE(3) -> T0 landed
    gload16(pA0, dA);      gload16(pB0, dB0);          gload16(pB1, dB1);
    gload16(pA0 + 32, dA + 12288); gload16(pB0 + 32, dB0 + 12288); gload16(pB1 + 32, dB1 + 12288);
    GATE(3);

    // main loop: tiles 0..29; stage tile j+2 into slot ws; GATE(3) leaves
    // T+2's 3 loads in flight (T+1 landed when its tile begins).
    int rs = 0, ws = 2;
    size_t ko = 64;
    #pragma unroll 1
    for (int j = 0; j < 30; ++j) {
        const char* rA_ = ldsA_rd + rs * 24576;
        const char* rB_ = ldsB_rd + rs * 24576;
        short8 av[4], bv[4];
        #pragma unroll
        for (int i_ = 0; i_ < 4; ++i_) av[i_] = *(const short8*)(rA_ + i_ * 1024);
        #pragma unroll
        for (int j_ = 0; j_ < 4; ++j_) bv[j_] = *(const short8*)(rB_ + j_ * 1024);
        int wso = ws * 12288;
        gload16(pA0 + ko, dA + wso);
        gload16(pB0 + ko, dB0 + wso);
        gload16(pB1 + ko, dB1 + wso);
        SBAR();
        __builtin_amdgcn_s_setprio(1);
        MFMA16(acc, av, bv);
        __builtin_amdgcn_s_setprio(0);
        GATE(3);
        rs = (rs == 2) ? 0 : rs + 1;
        ws = (ws == 2) ? 0 : ws + 1;
        ko += 32;
    }
    // tile 30: no stage; drain T31
    {
        const char* rA_ = ldsA_rd + rs * 24576;
        const char* rB_ = ldsB_rd + rs * 24576;
        short8 av[4], bv[4];
        #pragma unroll
        for (int i_ = 0; i_ < 4; ++i_) av[i_] = *(const short8*)(rA_ + i_ * 1024);
        #pragma unroll
        for (int j_ = 0; j_ < 4; ++j_) bv[j_] = *(const short8*)(rB_ + j_ * 1024);
        SBAR();
        __builtin_amdgcn_s_setprio(1);
        MFMA16(acc, av, bv);
        __builtin_amdgcn_s_setprio(0);
        GATE(0);
        rs = (rs == 2) ? 0 : rs + 1;
    }
    // tile 31
    {
        const char* rA_ = ldsA_rd + rs * 24576;
        const char* rB_ = ldsB_rd + rs * 24576;
        short8 av[4], bv[4];
        #pragma unroll
        for (int i_ = 0; i_ < 4; ++i_) av[i_] = *(const short8*)(rA_ + i_ * 1024);
        #pragma unroll
        for (int j_ = 0; j_ < 4; ++j_) bv[j_] = *(const short8*)(rB_ + j_ * 1024);
        SBAR();
        __builtin_amdgcn_s_setprio(1);
        MFMA16(acc, av, bv);
        __builtin_amdgcn_s_setprio(0);
    }

    // epilogue: row-major line completion. C/D: col=lane&15, row=quad*4+r
    int col = lane & 15;
    int quad = lane >> 4;
    float bs[4];
    #pragma unroll
    for (int jf = 0; jf < 4; ++jf) bs[jf] = bias[n0 + wn * 64 + jf * 16 + col];
    bool isU = (n0 < D_MODEL);               // uniform per block
    int nbase = isU ? (n0 + wn * 64 + col) : (n0 - D_MODEL + wn * 64 + col);
    unsigned short* obase = isU ? u_bf : zs;
    #pragma unroll
    for (int i = 0; i < 4; ++i) {
        #pragma unroll
        for (int r = 0; r < 4; ++r) {
            int m = m0 + wm * 64 + i * 16 + quad * 4 + r;
            unsigned short* orow = obase + (size_t)m * D_MODEL + nbase;
            #pragma unroll
            for (int jf = 0; jf < 4; ++jf) {
                float v = acc[i][jf][r] + bs[jf];
                if (!isU) v = v / (1.0f + __expf(-v));
                orow[jf * 16] = f2bf(v);
            }
        }
    }
}

// ============================================================================
// GEMM2: 128x256 tile, BK=32, 4 LDS slots (24KB each), lead-3 pipeline.
// Unchanged from R4 (isolation).
// ============================================================================
#define STAGE2(J) { size_t ko_ = (size_t)(J) * 32; int so_ = ((J) & 3) * 12288; \
    gload16(pA0 + ko_, dA + so_); gload16(pB0 + ko_, dB0 + so_); gload16(pB1 + ko_, dB1 + so_); }

#define G2_TILE(J, DOSTAGE, TRAIL) { \
    const int slot_ = (J) & 3; \
    const char* rA_ = ldsA_rd + slot_ * 24576; \
    const char* rB_ = ldsB_rd + slot_ * 24576; \
    short8 av[4], bv[4]; \
    _Pragma("unroll") for (int i_ = 0; i_ < 4; ++i_) av[i_] = *(const short8*)(rA_ + i_ * 1024); \
    _Pragma("unroll") for (int j_ = 0; j_ < 4; ++j_) bv[j_] = *(const short8*)(rB_ + j_ * 1024); \
    if (DOSTAGE) { STAGE2((J) + 3); } \
    SBAR(); \
    __builtin_amdgcn_s_setprio(1); \
    MFMA16(acc, av, bv); \
    __builtin_amdgcn_s_setprio(0); \
    TRAIL; \
}

__global__ __launch_bounds__(512, 2) void gemm2_kernel(const unsigned short* __restrict__ A,
                                                       const unsigned short* __restrict__ Bt,
                                                       const float* __restrict__ bias,
                                                       float* __restrict__ out_f,
                                                       const float* __restrict__ resid) {
    __shared__ __align__(16) unsigned short lds[4][12288];   // 96 KB
    const int K = D_MODEL;

    int t = threadIdx.x;
    int lane = t & 63;
    int wave = t >> 6;
    int wm = wave >> 2;
    int wn = wave & 3;

    int bid = blockIdx.x;
    int swz = (bid & 7) * 32 + (bid >> 3);
    int m0 = (swz >> 2) * 128;
    int n0 = (swz & 3) * 256;

    int srow = lane >> 2;
    int sk = ((lane & 3) * 8) ^ ((lane & 32) >> 1);
    const unsigned short* pA0 = A  + (size_t)(m0 + wave * 16 + srow) * K + sk;
    const unsigned short* pB0 = Bt + (size_t)(n0 + wave * 16 + srow) * K + sk;
    const unsigned short* pB1 = pB0 + (size_t)128 * K;

    unsigned short* dA  = &lds[0][wave * 512];
    unsigned short* dB0 = &lds[0][4096 + wave * 512];
    unsigned short* dB1 = &lds[0][8192 + wave * 512];

    int off_base = (lane & 15) * 64 + (((lane >> 4) * 16) ^ ((lane & 8) * 4));
    const char* ldsA_rd = (const char*)(&lds[0][0]) + wm * 4096 + off_base;
    const char* ldsB_rd = (const char*)(&lds[0][0]) + 8192 + wn * 4096 + off_base;

    f32x4 acc[4][4] = {};

    STAGE2(0); STAGE2(1); STAGE2(2);
    GATE(6);

    #pragma unroll 1
    for (int j = 0; j < 29; ++j) { G2_TILE(j, true, GATE(6)); }
    G2_TILE(29, false, GATE(3));
    G2_TILE(30, false, GATE(0));
    G2_TILE(31, false, (void)0);

    int col = lane & 15;
    int quad = lane >> 4;
    float bs[4];
    #pragma unroll
    for (int jf = 0; jf < 4; ++jf) bs[jf] = bias[n0 + wn * 64 + jf * 16 + col];
    #pragma unroll
    for (int i = 0; i < 4; ++i) {
        #pragma unroll
        for (int r = 0; r < 4; ++r) {
            int m = m0 + wm * 64 + i * 16 + quad * 4 + r;
            const float* rrow = resid + (size_t)m * D_MODEL + n0 + wn * 64 + col;
            float* orow = out_f + (size_t)m * D_MODEL + n0 + wn * 64 + col;
            #pragma unroll
            for (int jf = 0; jf < 4; ++jf) {
                float y = acc[i][jf][r] + bs[jf] + rrow[jf * 16];
                y = fminf(10.0f, fmaxf(-10.0f, y));
                orow[jf * 16] = y;
            }
        }
    }
}

// ============================================================================
// Fused SSM scan (R4, unchanged): scan1 + combine + scan2 in one kernel.
// ============================================================================
__global__ __launch_bounds__(512) void scan_fused_kernel(const unsigned short* __restrict__ u,
                                                         const unsigned short* __restrict__ zs,
                                                         const float* __restrict__ A_log,
                                                         const float* __restrict__ Bp,
                                                         const float* __restrict__ Cp,
                                                         const float* __restrict__ log_dt,
                                                         unsigned short* __restrict__ yz) {
    __shared__ float S[N_CHUNK][D_STATE][17];   // 34,816 B; pad 17 vs bank aliasing

    int bid = blockIdx.x;
    int l  = (bid & 7) * 32 + (bid >> 3);   // bijective XCD-chunk swizzle
    int b  = l >> 6;                         // 0..3
    int dg = l & 63;                         // 0..63
    int t  = threadIdx.x;
    int c  = t >> 4;                         // chunk 0..31
    int dl = t & 15;
    int d  = dg * 16 + dl;

    // params
    float dt = fminf(1.0f, fmaxf(1e-4f, __expf(log_dt[d])));
    float ab[D_STATE];
    #pragma unroll
    for (int n = 0; n < D_STATE; n++) {
        float a = __expf(-__expf(A_log[d * D_STATE + n]) * dt);
        ab[n] = fminf(1.0f - 1e-8f, fmaxf(1e-8f, a));
    }

    // ---- pass 1: local chunk scan, cache u in registers ----
    size_t row0 = (size_t)(b * L_SEQ + c * C_LEN);
    const unsigned short* up = u + row0 * D_MODEL + d;

    unsigned int uc[32];          // 64 bf16 packed as 32 x u32
    float P[D_STATE];
    #pragma unroll
    for (int n = 0; n < D_STATE; n++) P[n] = 0.0f;
    #pragma unroll
    for (int tt = 0; tt < 32; tt++) {
        unsigned int lo = up[(size_t)(2 * tt) * D_MODEL];
        unsigned int hi = up[(size_t)(2 * tt + 1) * D_MODEL];
        uc[tt] = lo | (hi << 16);
        float u0 = __uint_as_float(lo << 16);
        float u1 = __uint_as_float(hi << 16);
        #pragma unroll
        for (int n = 0; n < D_STATE; n++) P[n] = fmaf(ab[n], P[n], u0);
        #pragma unroll
        for (int n = 0; n < D_STATE; n++) P[n] = fmaf(ab[n], P[n], u1);
    }

    // publish chunk-final states
    #pragma unroll
    for (int n = 0; n < D_STATE; n++) S[c][n][dl] = P[n];

    // aP = a^64 (uniform across chunks -> constant-coefficient prefix valid)
    float m[D_STATE];
    #pragma unroll
    for (int n = 0; n < D_STATE; n++) {
        float a2 = ab[n];
        #pragma unroll
        for (int q = 0; q < 6; q++) a2 = a2 * a2;
        m[n] = a2;
    }
    __syncthreads();

    // ---- Hillis-Steele inclusive prefix over c: P[c] += m * P[c-k] ----
    #pragma unroll
    for (int k = 1; k < N_CHUNK; k <<= 1) {
        float tmp[D_STATE];
        #pragma unroll
        for (int n = 0; n < D_STATE; n++) tmp[n] = (c >= k) ? S[c - k][n][dl] : 0.0f;
        __syncthreads();
        #pragma unroll
        for (int n = 0; n < D_STATE; n++) {
            P[n] = fmaf(m[n], tmp[n], P[n]);
            S[c][n][dl] = P[n];
        }
        #pragma unroll
        for (int n = 0; n < D_STATE; n++) m[n] = m[n] * m[n];
        __syncthreads();
    }

    // ---- pass 2: rescan with exclusive prefix init, fuse z-gate ----
    float s2[D_STATE];
    #pragma unroll
    for (int n = 0; n < D_STATE; n++) s2[n] = (c == 0) ? 0.0f : S[c - 1][n][dl];

    float cb[D_STATE];
    #pragma unroll
    for (int n = 0; n < D_STATE; n++)
        cb[n] = Cp[d * D_STATE + n] * Bp[d * D_STATE + n] * dt;

    const unsigned short* zp = zs + row0 * D_MODEL + d;
    unsigned short* yp = yz + row0 * D_MODEL + d;

    #pragma unroll
    for (int tt = 0; tt < 32; tt++) {
        unsigned int w = uc[tt];
        float u0 = __uint_as_float(w << 16);
        float u1 = __uint_as_float(w & 0xFFFF0000u);
        float y0 = 0.0f, y1 = 0.0f;
        #pragma unroll
        for (int n = 0; n < D_STATE; n++) s2[n] = fmaf(ab[n], s2[n], u0);
        #pragma unroll
        for (int n = 0; n < D_STATE; n++) y0 = fmaf(cb[n], s2[n], y0);
        #pragma unroll
        for (int n = 0; n < D_STATE; n++) s2[n] = fmaf(ab[n], s2[n], u1);
        #pragma unroll
        for (int n = 0; n < D_STATE; n++) y1 = fmaf(cb[n], s2[n], y1);
        float z0 = bf2f(zp[(size_t)(2 * tt) * D_MODEL]);
        float z1 = bf2f(zp[(size_t)(2 * tt + 1) * D_MODEL]);
        yp[(size_t)(2 * tt) * D_MODEL]     = f2bf(y0 * z0);
        yp[(size_t)(2 * tt + 1) * D_MODEL] = f2bf(y1 * z1);
    }
}

extern "C" void kernel_launch(void* const* d_in, const int* in_sizes, int n_in,
                              void* d_out, int out_size, void* d_ws, size_t ws_size,
                              hipStream_t stream) {
    const float* x       = (const float*)d_in[0];
    const float* A_log   = (const float*)d_in[1];
    const float* B_param = (const float*)d_in[2];
    const float* C_param = (const float*)d_in[3];
    const float* log_dt  = (const float*)d_in[4];
    const float* in_w    = (const float*)d_in[5];
    const float* in_b    = (const float*)d_in[6];
    const float* out_w   = (const float*)d_in[7];
    const float* out_b   = (const float*)d_in[8];
    const float* ln_g    = (const float*)d_in[9];
    const float* ln_b    = (const float*)d_in[10];
    float* out = (float*)d_out;

    char* ws = (char*)d_ws;
    size_t off = 0;
    unsigned short* xn = (unsigned short*)(ws + off); off += (size_t)M_ROWS * D_MODEL * 2;        // 16 MB
    unsigned short* w1 = (unsigned short*)(ws + off); off += (size_t)2 * D_MODEL * D_MODEL * 2;   // 4 MB
    unsigned short* u  = (unsigned short*)(ws + off); off += (size_t)M_ROWS * D_MODEL * 2;        // 16 MB
    unsigned short* zs = (unsigned short*)(ws + off); off += (size_t)M_ROWS * D_MODEL * 2;        // 16 MB
    unsigned short* yz = (unsigned short*)(ws + off); off += (size_t)M_ROWS * D_MODEL * 2;        // 16 MB
    unsigned short* w2 = (unsigned short*)(ws + off); off += (size_t)D_MODEL * D_MODEL * 2;       // 2 MB

    // fused LN + weight conversion
    prep_kernel<<<M_ROWS + 2048 + 1024, 256, 0, stream>>>(x, ln_g, ln_b, xn, in_w, w1, out_w, w2);

    // GEMM1: (8192x1024) @ (2048x1024)^T -> u bf16 / silu(z) bf16
    gemm1_kernel<<<512, 512, 0, stream>>>(xn, w1, in_b, u, zs);

    // fused chunked SSM scan
    scan_fused_kernel<<<256, 512, 0, stream>>>(u, zs, A_log, B_param, C_param, log_dt, yz);

    // GEMM2: (8192x1024) @ (1024x1024)^T + resid, clip
    gemm2_kernel<<<256, 512, 0, stream>>>(yz, w2, out_b, out, x);
}